// Round 12
// baseline (894.599 us; speedup 1.0000x reference)
//
#include <hip/hip_runtime.h>
#include <stdint.h>
#include <stddef.h>

// ---------------------------------------------------------------------------
// Fused GQA attention block: QKV proj + half-split RoPE + flash attention +
// output proj. fp16 MFMA (16x16x32) everywhere, fp32 accumulate/softmax.
// R12: attention reworked for occupancy: KVB=32, ring-3 K/V LDS (56KB total
// -> 2 blocks/CU = 16 waves), counted vmcnt(2) top-of-tile (never drains in
// steady state), stage(t+2) post-barrier. GEMM = R11 (best measured).
// ---------------------------------------------------------------------------

typedef _Float16 half_t;
typedef __attribute__((ext_vector_type(4))) _Float16 f16x4;
typedef __attribute__((ext_vector_type(8))) _Float16 f16x8;
typedef __attribute__((ext_vector_type(4))) float f32x4;

#define NB 2
#define NL 2048
#define ND 4096
#define NH 32
#define NKV 8
#define NHD 128
#define NG 4               // H / KV
#define NQKV 6144          // H*HD + 2*KV*HD
#define QK_SCALE 0.08838834764831845f   // HD^-0.5
#define RLOG2E 1.4426950408889634f
#define M0 6.0f            // fixed softmax reference (scores ~N(0,1.64^2))
#define THR 8.0f           // defer-max threshold (fallback if mx > M0+THR)

// async global->LDS, 16B per lane. LDS dest must be wave-uniform base;
// lane i lands at base + i*16 (HW-defined linear scatter).
static __device__ __forceinline__ void gll16(const void* g, void* l) {
  __builtin_amdgcn_global_load_lds(
      (__attribute__((address_space(1))) void*)(void*)(g),
      (__attribute__((address_space(3))) void*)(l),
      16, 0, 0);
}

// ---------------------------------------------------------------------------
// elementwise fp32 -> fp16 (vectorized: float4 in, 4xfp16 out)
// ---------------------------------------------------------------------------
__global__ void convert_f32_f16_kernel(const float* __restrict__ in,
                                       half_t* __restrict__ out, int n4) {
  int i = blockIdx.x * 256 + threadIdx.x;
  if (i >= n4) return;
  const float4 v = reinterpret_cast<const float4*>(in)[i];
  f16x4 o;
  o[0] = (half_t)v.x; o[1] = (half_t)v.y; o[2] = (half_t)v.z; o[3] = (half_t)v.w;
  reinterpret_cast<f16x4*>(out)[i] = o;
}

// ---------------------------------------------------------------------------
// W [K,N] fp32 row-major  ->  Wt [N,K] fp16 row-major (LDS 32x32 tile transpose)
// ---------------------------------------------------------------------------
__global__ void wtrans_kernel(const float* __restrict__ W,
                              half_t* __restrict__ Wt, int K, int N) {
  __shared__ float tile[32][33];
  const int n0 = blockIdx.x * 32;
  const int k0 = blockIdx.y * 32;
  const int tx = threadIdx.x, ty = threadIdx.y;   // block (32,8)
#pragma unroll
  for (int r = 0; r < 32; r += 8)
    tile[ty + r][tx] = W[(size_t)(k0 + ty + r) * N + n0 + tx];
  __syncthreads();
#pragma unroll
  for (int r = 0; r < 32; r += 8)
    Wt[(size_t)(n0 + ty + r) * K + k0 + tx] = (half_t)tile[tx][ty + r];
}

// ---------------------------------------------------------------------------
// RoPE sin/cos table: tab[l*64+d] = {cos(l*invfreq(d)), sin(l*invfreq(d))}
// ---------------------------------------------------------------------------
__global__ void ropetab_kernel(float2* __restrict__ tab) {
  const int idx = blockIdx.x * 256 + threadIdx.x;   // NL*64 entries
  const int d = idx & 63;
  const int l = idx >> 6;
  const float inv_freq = exp2f(-(float)d * 0.20762050593045935f);
  const float ang = (float)l * inv_freq;
  float sn, cs;
  __sincosf(ang, &sn, &cs);
  tab[idx] = make_float2(cs, sn);
}

// ---------------------------------------------------------------------------
// GEMM (R11, best measured): 256x256 tile, 8 waves, BK=64 as 2 K-halves,
// 2 phases/K-tile, 32 MFMA/phase, one barrier + one combined vmcnt+lgkm wait
// per phase. See R11 comments for the full RAW/WAR audit.
// ---------------------------------------------------------------------------
template <typename OutT>
__global__ __launch_bounds__(512, 2) void gemm256_kernel(
    const half_t* __restrict__ A, const half_t* __restrict__ Bt,
    const float* __restrict__ B0, const float* __restrict__ B1,
    const float* __restrict__ B2, OutT* __restrict__ C,
    int M, int N, int K) {
  __shared__ __align__(16) half_t As[2][2][256 * 32];   // [buf][kh] 16KB each
  __shared__ __align__(16) half_t Bs[2][2][256 * 32];

  const int tid = threadIdx.x;
  const int wave = tid >> 6, lane = tid & 63;
  const int r16 = lane & 15, quad = lane >> 4;
  const int wm = wave >> 2, wn = wave & 3;   // 2M x 4N wave grid

  // T1: XCD-chunked swizzle of linear block id (nwg % 8 == 0 for our grids)
  const int nbx = N >> 8;
  const int lid = (int)(blockIdx.y * gridDim.x + blockIdx.x);
  const int nwg = (int)(gridDim.x * gridDim.y);
  const int cpx = nwg >> 3;
  const int swz = (lid & 7) * cpx + (lid >> 3);
  const int brow = (swz / nbx) * 256;
  const int bcol = (swz % nbx) * 256;

  const int NT = K >> 6;   // K/64 tiles

  auto stA = [&](int t, int kh) {
    const int buf = t & 1;
    const int k0 = (t << 6) + (kh << 5);
#pragma unroll
    for (int j = 0; j < 2; ++j) {
      const int s = j * 512 + wave * 64 + lane;
      const int row = s >> 2;
      const int cg = (s & 3) ^ ((row >> 1) & 3);
      gll16(A + (size_t)(brow + row) * K + k0 + cg * 8,
            &As[buf][kh][(j * 512 + wave * 64) * 8]);
    }
  };
  auto stB = [&](int t, int kh) {
    const int buf = t & 1;
    const int k0 = (t << 6) + (kh << 5);
#pragma unroll
    for (int j = 0; j < 2; ++j) {
      const int s = j * 512 + wave * 64 + lane;
      const int row = s >> 2;
      const int cg = (s & 3) ^ ((row >> 1) & 3);
      gll16(Bt + (size_t)(bcol + row) * K + k0 + cg * 8,
            &Bs[buf][kh][(j * 512 + wave * 64) * 8]);
    }
  };

  f32x4 acc[8][4] = {};
  const int csw = (quad ^ ((r16 >> 1) & 3)) << 3;   // swizzled chunk (halfs)

  stA(0, 0); stB(0, 0); stA(0, 1); stB(0, 1); stA(1, 0); stB(1, 0);
  asm volatile("s_waitcnt vmcnt(8)" ::: "memory");
  __builtin_amdgcn_s_barrier();

  for (int t = 0; t < NT; ++t) {
    const int buf = t & 1;
    const half_t* Ak0 = &As[buf][0][0];
    const half_t* Ak1 = &As[buf][1][0];
    const half_t* Bk0 = &Bs[buf][0][0];
    const half_t* Bk1 = &Bs[buf][1][0];
    f16x8 af[4], bf[4], ah[4];

    // ============ PA: kc0, 32 MFMA ============
#pragma unroll
    for (int mi = 0; mi < 4; ++mi)
      af[mi] = *reinterpret_cast<const f16x8*>(
          &Ak0[(wm * 128 + mi * 16 + r16) * 32 + csw]);
#pragma unroll
    for (int ni = 0; ni < 4; ++ni)
      bf[ni] = *reinterpret_cast<const f16x8*>(
          &Bk0[(wn * 64 + ni * 16 + r16) * 32 + csw]);
#pragma unroll
    for (int mi = 0; mi < 4; ++mi)
      ah[mi] = *reinterpret_cast<const f16x8*>(
          &Ak0[(wm * 128 + 64 + mi * 16 + r16) * 32 + csw]);
    if (t + 1 < NT) {
      stA(t + 1, 1); stB(t + 1, 1);
      asm volatile("s_waitcnt vmcnt(8) lgkmcnt(0)" ::: "memory");
    } else {
      asm volatile("s_waitcnt vmcnt(4) lgkmcnt(0)" ::: "memory");
    }
    __builtin_amdgcn_sched_barrier(0);
    __builtin_amdgcn_s_barrier();
    __builtin_amdgcn_sched_barrier(0);
    __builtin_amdgcn_s_setprio(1);
#pragma unroll
    for (int mi = 0; mi < 4; ++mi)
#pragma unroll
      for (int ni = 0; ni < 4; ++ni)
        acc[mi][ni] = __builtin_amdgcn_mfma_f32_16x16x32_f16(
            af[mi], bf[ni], acc[mi][ni], 0, 0, 0);
#pragma unroll
    for (int mi = 0; mi < 4; ++mi)
#pragma unroll
      for (int ni = 0; ni < 4; ++ni)
        acc[mi + 4][ni] = __builtin_amdgcn_mfma_f32_16x16x32_f16(
            ah[mi], bf[ni], acc[mi + 4][ni], 0, 0, 0);
    __builtin_amdgcn_s_setprio(0);

    // ============ PB: kc1, 32 MFMA ============
#pragma unroll
    for (int mi = 0; mi < 4; ++mi)
      af[mi] = *reinterpret_cast<const f16x8*>(
          &Ak1[(wm * 128 + mi * 16 + r16) * 32 + csw]);
#pragma unroll
    for (int ni = 0; ni < 4; ++ni)
      bf[ni] = *reinterpret_cast<const f16x8*>(
          &Bk1[(wn * 64 + ni * 16 + r16) * 32 + csw]);
#pragma unroll
    for (int mi = 0; mi < 4; ++mi)
      ah[mi] = *reinterpret_cast<const f16x8*>(
          &Ak1[(wm * 128 + 64 + mi * 16 + r16) * 32 + csw]);
    if (t + 2 < NT) {
      stA(t + 2, 0); stB(t + 2, 0);
      asm volatile("s_waitcnt vmcnt(8) lgkmcnt(0)" ::: "memory");
    } else if (t + 1 < NT) {
      asm volatile("s_waitcnt vmcnt(8) lgkmcnt(0)" ::: "memory");
    } else {
      asm volatile("s_waitcnt vmcnt(0) lgkmcnt(0)" ::: "memory");
    }
    __builtin_amdgcn_sched_barrier(0);
    __builtin_amdgcn_s_barrier();
    __builtin_amdgcn_sched_barrier(0);
    __builtin_amdgcn_s_setprio(1);
#pragma unroll
    for (int mi = 0; mi < 4; ++mi)
#pragma unroll
      for (int ni = 0; ni < 4; ++ni)
        acc[mi][ni] = __builtin_amdgcn_mfma_f32_16x16x32_f16(
            af[mi], bf[ni], acc[mi][ni], 0, 0, 0);
#pragma unroll
    for (int mi = 0; mi < 4; ++mi)
#pragma unroll
      for (int ni = 0; ni < 4; ++ni)
        acc[mi + 4][ni] = __builtin_amdgcn_mfma_f32_16x16x32_f16(
            ah[mi], bf[ni], acc[mi + 4][ni], 0, 0, 0);
    __builtin_amdgcn_s_setprio(0);
  }

  // epilogue: D row = (lane>>4)*4 + reg, col = lane&15 (verified C/D layout)
#pragma unroll
  for (int ni = 0; ni < 4; ++ni) {
    const int col = bcol + wn * 64 + ni * 16 + r16;
    float bv = 0.0f;
    if (B0) bv = (col < ND) ? B0[col]
                            : (col < ND + NKV * NHD ? B1[col - ND]
                                                    : B2[col - ND - NKV * NHD]);
#pragma unroll
    for (int mi = 0; mi < 8; ++mi) {
      const int row0 = brow + wm * 128 + mi * 16 + quad * 4;
#pragma unroll
      for (int i = 0; i < 4; ++i)
        C[(size_t)(row0 + i) * N + col] = (OutT)(acc[mi][ni][i] + bv);
    }
  }
}

// ---------------------------------------------------------------------------
// RoPE (half-split, table-driven) + reshape for Q and K from merged raw fp16.
// ---------------------------------------------------------------------------
__global__ void ropepack_kernel(const half_t* __restrict__ rawh,
                                const float2* __restrict__ tab,
                                half_t* __restrict__ qb,
                                half_t* __restrict__ kb) {
  const size_t idx = (size_t)blockIdx.x * 256 + threadIdx.x;
  const int d = (int)(idx & 63);
  size_t t = idx >> 6;
  const int hp = (int)(t % (NH + NKV)); t /= (NH + NKV);
  const int l = (int)(t % NL);
  const int b = (int)(t / NL);
  const bool isQ = hp < NH;
  const int col0 = isQ ? hp * NHD : ND + (hp - NH) * NHD;
  const half_t* src = rawh + ((size_t)b * NL + l) * NQKV + col0;
  const float x1 = (float)src[d];
  const float x2 = (float)src[d + 64];
  const float2 cssn = tab[(size_t)l * 64 + d];
  const float scale = isQ ? QK_SCALE : 1.0f;
  half_t* dst = isQ ? qb + ((size_t)(b * NH + hp) * NL + l) * NHD
                    : kb + ((size_t)(b * NKV + (hp - NH)) * NL + l) * NHD;
  dst[d]      = (half_t)((x1 * cssn.x - x2 * cssn.y) * scale);
  dst[d + 64] = (half_t)((x2 * cssn.x + x1 * cssn.y) * scale);
}

// ---------------------------------------------------------------------------
// V: merged raw fp16 cols [5120,6144) -> Vt [B, KV, HD, L] fp16 (transpose)
// ---------------------------------------------------------------------------
__global__ void vtrans16_kernel(const half_t* __restrict__ rawh,
                                half_t* __restrict__ Vt) {
  __shared__ half_t tile[32][34];
  const int bkv = blockIdx.z;
  const int l0 = blockIdx.x * 32;
  const int d0 = blockIdx.y * 32;
  const int b = bkv / NKV, kvh = bkv % NKV;
  const int tx = threadIdx.x, ty = threadIdx.y;   // block (32,8)
#pragma unroll
  for (int r = 0; r < 32; r += 8)
    tile[ty + r][tx] = rawh[(size_t)(b * NL + l0 + ty + r) * NQKV
                            + ND + NKV * NHD + kvh * NHD + d0 + tx];
  __syncthreads();
  half_t* dst = Vt + (size_t)bkv * NHD * NL;
#pragma unroll
  for (int r = 0; r < 32; r += 8)
    dst[(size_t)(d0 + ty + r) * NL + l0 + tx] = tile[tx][ty + r];
}

// ---------------------------------------------------------------------------
// Flash attention (non-causal, GQA). 8 waves x 32 Q-rows = 256 rows/block.
// R12: KVB=32, ring-3 K/V (3x8KB each) + 8KB P = 56KB LDS -> 2 blocks/CU
// (16 waves). Counted vmcnt(2) at top of tile (retires tile t only; t+1
// stays in flight; no drain in steady state); stage(t+2) issued after the
// barrier into the buffer tile t-1 vacated (its reads were consumed by
// MFMAs before each wave reached this barrier -> WAR safe; vmcnt+barrier
// gives block-wide RAW residency). Softmax: fixed ref M0, per-lane deferred
// row-sum, rare wave-uniform fallback rescale. Per-quad conflict-free
// swizzles: K c^(row&7), V c^((row>>1)&3), P write c^quad / read
// c^((r16>>2)&3). T5 setprio on MFMA clusters.
// ---------------------------------------------------------------------------
#define KVB 32

__global__ __launch_bounds__(512, 4) void attn_kernel(
    const half_t* __restrict__ Q,   // [B,H,L,HD] scaled
    const half_t* __restrict__ Kh,  // [B,KV,L,HD]
    const half_t* __restrict__ Vt,  // [B,KV,HD,L]
    half_t* __restrict__ O) {
  __shared__ half_t Ks[3][KVB * NHD];   // 3 x 8KB
  __shared__ half_t Vs[3][NHD * KVB];   // 3 x 8KB
  __shared__ half_t Ps[8][16 * KVB];    // 8KB, per-wave P tile

  const int tid = threadIdx.x;
  const int wave = tid >> 6, lane = tid & 63;
  const int r16 = lane & 15, quad = lane >> 4;
  const int r7 = r16 & 7;

  // XCD-chunked swizzle: 64 consecutive work-items per XCD (512 = 8*64)
  const int bid = (int)blockIdx.x;
  const int swz = (bid & 7) * 64 + (bid >> 3);
  const int nqt = NL / 256;                    // 8
  const int bh = swz / nqt, qt = swz % nqt;
  const int b = bh / NH, h = bh % NH;
  const int kvh = h / NG;

  const int qrow0 = qt * 256 + wave * 32;
  const half_t* Qb = Q  + ((size_t)(b * NH + h) * NL + qrow0) * NHD;
  const half_t* Kb = Kh + ((size_t)(b * NKV + kvh) * NL) * NHD;
  const half_t* Vb = Vt + ((size_t)(b * NKV + kvh) * NHD) * NL;
  half_t* Pw = &Ps[wave][0];

  // stage tile at n0 into ring slot buf: K 512 chunks + V 512 chunks,
  // 1 chunk per thread each (2 vmcnt ops per stage per wave).
  auto stage = [&](int buf, int n0) {
    const int slot = wave * 64 + lane;
    {
      const int row = slot >> 4;                  // key row 0..31
      const int c = (slot & 15) ^ (row & 7);
      gll16(Kb + (size_t)(n0 + row) * NHD + c * 8, &Ks[buf][slot * 8]);
    }
    {
      const int row = slot >> 2;                  // d row 0..127
      const int c = (slot & 3) ^ ((row >> 1) & 3);
      gll16(Vb + (size_t)row * NL + n0 + c * 8, &Vs[buf][slot * 8]);
    }
  };

  stage(0, 0);

  // Q fragments: 2 row-tiles x 4 k-chunks (8 vmcnt ops)
  f16x8 qf[2][4];
#pragma unroll
  for (int rt = 0; rt < 2; ++rt)
#pragma unroll
    for (int c = 0; c < 4; ++c)
      qf[rt][c] = *reinterpret_cast<const f16x8*>(
          &Qb[(size_t)(rt * 16 + r16) * NHD + c * 32 + quad * 8]);

  stage(1, KVB);

  f32x4 oacc[2][8];
  float m_run[2][4], lsum[2][4];
#pragma unroll
  for (int rt = 0; rt < 2; ++rt) {
#pragma unroll
    for (int i = 0; i < 4; ++i) { m_run[rt][i] = M0; lsum[rt][i] = 0.0f; }
#pragma unroll
    for (int dt = 0; dt < 8; ++dt) oacc[rt][dt] = (f32x4){0.f, 0.f, 0.f, 0.f};
  }

  const int NT = NL / KVB;   // 64
  const int chv = (quad ^ ((r16 >> 1) & 3)) * 8;       // V read chunk
  const int chp = (quad ^ ((r16 >> 2) & 3)) * 8;       // P read chunk
  int cur = 0, stg = 2;

  for (int t = 0; t < NT; ++t) {
    // retire tile t (own share); barrier makes it block-wide
    if (t + 1 < NT) {
      asm volatile("s_waitcnt vmcnt(2)" ::: "memory");
    } else {
      asm volatile("s_waitcnt vmcnt(0)" ::: "memory");
    }
    __builtin_amdgcn_s_barrier();
    __builtin_amdgcn_sched_barrier(0);
    if (t + 2 < NT) stage(stg, (t + 2) * KVB);

    const half_t* Kc = &Ks[cur][0];
    const half_t* Vc = &Vs[cur][0];

    // ---- S = Q K^T (swizzled K reads) ----
    f32x4 s[2][2] = {};
    __builtin_amdgcn_s_setprio(1);
#pragma unroll
    for (int c = 0; c < 4; ++c) {
      const int ch = ((c * 4 + quad) ^ r7) * 8;
#pragma unroll
      for (int nt = 0; nt < 2; ++nt) {
        f16x8 kf = *reinterpret_cast<const f16x8*>(&Kc[(nt * 16 + r16) * NHD + ch]);
        s[0][nt] = __builtin_amdgcn_mfma_f32_16x16x32_f16(qf[0][c], kf, s[0][nt], 0, 0, 0);
        s[1][nt] = __builtin_amdgcn_mfma_f32_16x16x32_f16(qf[1][c], kf, s[1][nt], 0, 0, 0);
      }
    }
    __builtin_amdgcn_s_setprio(0);

    // ---- fallback check: any lane-local score above running ref? ----
    float mx[2][4];
    bool need = false;
#pragma unroll
    for (int rt = 0; rt < 2; ++rt)
#pragma unroll
      for (int i = 0; i < 4; ++i) {
        mx[rt][i] = fmaxf(s[rt][0][i], s[rt][1][i]);
        need = need || (mx[rt][i] > m_run[rt][i] + THR);
      }
    if (__any(need ? 1 : 0)) {   // rare: full reduce + rescale (correctness)
#pragma unroll
      for (int rt = 0; rt < 2; ++rt)
#pragma unroll
        for (int i = 0; i < 4; ++i) {
          float m = mx[rt][i];
#pragma unroll
          for (int off = 1; off < 16; off <<= 1)
            m = fmaxf(m, __shfl_xor(m, off));
          const float mn = fmaxf(m_run[rt][i], m);
          const float corr = exp2f((m_run[rt][i] - mn) * RLOG2E);
          m_run[rt][i] = mn;
          lsum[rt][i] *= corr;
#pragma unroll
          for (int dt = 0; dt < 8; ++dt) oacc[rt][dt][i] *= corr;
        }
    }

    // ---- P = exp(S - m), per-lane partial sums, swizzled LDS writes ----
    f16x8 pa[2];
#pragma unroll
    for (int rt = 0; rt < 2; ++rt) {
#pragma unroll
      for (int i = 0; i < 4; ++i) {
        const float mrl = m_run[rt][i] * RLOG2E;
        const float p0 = exp2f(s[rt][0][i] * RLOG2E - mrl);
        const float p1 = exp2f(s[rt][1][i] * RLOG2E - mrl);
        lsum[rt][i] += p0 + p1;
        const int row = quad * 4 + i;
        Pw[row * KVB + (((r16 >> 3) ^ quad) * 8) + r7] = (half_t)p0;
        Pw[row * KVB + (((2 + (r16 >> 3)) ^ quad) * 8) + r7] = (half_t)p1;
      }
      // A-fragment (wave-private LDS; in-order DS pipe, no barrier)
      pa[rt] = *reinterpret_cast<const f16x8*>(&Pw[r16 * KVB + chp]);
    }

    // ---- O += P V (swizzled V reads, shared across both row-tiles) ----
    __builtin_amdgcn_s_setprio(1);
#pragma unroll
    for (int dt = 0; dt < 8; ++dt) {
      const int row = dt * 16 + r16;
      f16x8 v = *reinterpret_cast<const f16x8*>(&Vc[row * KVB + chv]);
      oacc[0][dt] = __builtin_amdgcn_mfma_f32_16x16x32_f16(pa[0], v, oacc[0][dt], 0, 0, 0);
      oacc[1][dt] = __builtin_amdgcn_mfma_f32_16x16x32_f16(pa[1], v, oacc[1][dt], 0, 0, 0);
    }
    __builtin_amdgcn_s_setprio(0);

    cur = (cur == 2) ? 0 : cur + 1;
    stg = (stg == 2) ? 0 : stg + 1;
  }

  // ---- epilogue: one deferred row-sum reduce, normalize, write fp16 ----
  half_t* Ob = O + ((size_t)(b * NL) + qrow0) * (NH * NHD) + (size_t)h * NHD;
#pragma unroll
  for (int rt = 0; rt < 2; ++rt)
#pragma unroll
    for (int i = 0; i < 4; ++i) {
      float l = lsum[rt][i];
#pragma unroll
      for (int off = 1; off < 16; off <<= 1)
        l += __shfl_xor(l, off);
      const float inv = 1.0f / l;
      const int rl = rt * 16 + quad * 4 + i;
#pragma unroll
      for (int dt = 0; dt < 8; ++dt)
        Ob[(size_t)rl * (NH * NHD) + dt * 16 + r16] =
            (half_t)(oacc[rt][dt][i] * inv);
    }
}

// ---------------------------------------------------------------------------
extern "C" void kernel_launch(void* const* d_in, const int* in_sizes, int n_in,
                              void* d_out, int out_size, void* d_ws, size_t ws_size,
                              hipStream_t stream) {
  const float* x  = (const float*)d_in[0];
  const float* Wq = (const float*)d_in[1];
  const float* bq = (const float*)d_in[2];
  const float* Wk = (const float*)d_in[3];
  const float* bk = (const float*)d_in[4];
  const float* Wv = (const float*)d_in[5];
  const float* bv = (const float*)d_in[6];
  const float* Wo = (const float*)d_in[7];
  float* out = (float*)d_out;

  char* ws = (char*)d_ws;
  size_t off = 0;
  auto alloc = [&](size_t bytes) {
    size_t cur = off;
    off += (bytes + 255) & ~(size_t)255;
    return cur;
  };
  const size_t M = (size_t)NB * NL;  // 4096 token rows
  // buffer plan (~186 MB):
  half_t* xb   = (half_t*)(ws + alloc(M * ND * 2));            // x fp16; reused as AttnOut
  half_t* wqkv = (half_t*)(ws + alloc((size_t)NQKV * ND * 2)); // [Wq;Wk;Wv]^T; reused for Wo^T
  half_t* rawh = (half_t*)(ws + alloc(M * NQKV * 2));          // merged QKV raw fp16
  half_t* qb   = (half_t*)(ws + alloc(M * (size_t)(NH * NHD) * 2));
  half_t* kb   = (half_t*)(ws + alloc(M * (size_t)(NKV * NHD) * 2));
  half_t* vt   = (half_t*)(ws + alloc(M * (size_t)(NKV * NHD) * 2));
  float2* tab  = (float2*)(ws + alloc((size_t)NL * 64 * 8));   // RoPE cos/sin

  // 1) x -> fp16 ; RoPE table
  {
    int n4 = (int)(M * ND / 4);
    convert_f32_f16_kernel<<<dim3((n4 + 255) / 256), dim3(256), 0, stream>>>(x, xb, n4);
  }
  ropetab_kernel<<<dim3(NL * 64 / 256), dim3(256), 0, stream>>>(tab);

  // 2) weight transposes into merged [6144][4096] fp16
  wtrans_kernel<<<dim3(ND / 32, ND / 32), dim3(32, 8), 0, stream>>>(
      Wq, wqkv, ND, ND);
  wtrans_kernel<<<dim3((NKV * NHD) / 32, ND / 32), dim3(32, 8), 0, stream>>>(
      Wk, wqkv + (size_t)ND * ND, ND, NKV * NHD);
  wtrans_kernel<<<dim3((NKV * NHD) / 32, ND / 32), dim3(32, 8), 0, stream>>>(
      Wv, wqkv + (size_t)(ND + NKV * NHD) * ND, ND, NKV * NHD);

  // 3) merged QKV GEMM -> rawh fp16 (bias fused, 3-way select)
  gemm256_kernel<half_t><<<dim3(NQKV / 256, M / 256), dim3(512), 0, stream>>>(
      xb, wqkv, bq, bk, bv, rawh, (int)M, NQKV, ND);

  // 4) RoPE+pack Q,K (table-driven); transpose V
  ropepack_kernel<<<dim3((unsigned)(M * (NH + NKV) * 64 / 256)), dim3(256), 0, stream>>>(
      rawh, tab, qb, kb);
  vtrans16_kernel<<<dim3(NL / 32, NHD / 32, NB * NKV), dim3(32, 8), 0, stream>>>(rawh, vt);

  // 5) Wo^T into wqkv (dead after step 3; stream order guarantees safety)
  wtrans_kernel<<<dim3(ND / 32, ND / 32), dim3(32, 8), 0, stream>>>(Wo, wqkv, NH * NHD, ND);

  // 6) attention -> xb (reused as AttnOut, [B*L, H*HD] fp16)
  attn_kernel<<<dim3(NB * NH * (NL / 256)), dim3(512), 0, stream>>>(qb, kb, vt, xb);

  // 7) output projection -> d_out (fp32)
  gemm256_kernel<float><<<dim3(ND / 256, M / 256), dim3(512), 0, stream>>>(
      xb, wqkv, nullptr, nullptr, nullptr, out, (int)M, ND, ND);
}

// Round 13
// 676.428 us; speedup vs baseline: 1.3225x; 1.3225x over previous
//
#include <hip/hip_runtime.h>
#include <stdint.h>
#include <stddef.h>

// ---------------------------------------------------------------------------
// Fused GQA attention block: QKV proj + half-split RoPE + flash attention +
// output proj. fp16 MFMA (16x16x32) everywhere, fp32 accumulate/softmax.
// R13: attn launch_bounds fixed (512,2): R12's (512,4) was interpreted as
// 4 blocks/CU -> 64-VGPR cap -> accumulator spill to scratch (FETCH 25MB ->
// 1.35GB). Cap now 128 VGPR; 2 blocks/CU via 56KB LDS. mx[] array folded
// away to cut peak register pressure. GEMM = R11 (best measured, 230us).
// ---------------------------------------------------------------------------

typedef _Float16 half_t;
typedef __attribute__((ext_vector_type(4))) _Float16 f16x4;
typedef __attribute__((ext_vector_type(8))) _Float16 f16x8;
typedef __attribute__((ext_vector_type(4))) float f32x4;

#define NB 2
#define NL 2048
#define ND 4096
#define NH 32
#define NKV 8
#define NHD 128
#define NG 4               // H / KV
#define NQKV 6144          // H*HD + 2*KV*HD
#define QK_SCALE 0.08838834764831845f   // HD^-0.5
#define RLOG2E 1.4426950408889634f
#define M0 6.0f            // fixed softmax reference (scores ~N(0,1.64^2))
#define THR 8.0f           // defer-max threshold (fallback if mx > M0+THR)

// async global->LDS, 16B per lane. LDS dest must be wave-uniform base;
// lane i lands at base + i*16 (HW-defined linear scatter).
static __device__ __forceinline__ void gll16(const void* g, void* l) {
  __builtin_amdgcn_global_load_lds(
      (__attribute__((address_space(1))) void*)(void*)(g),
      (__attribute__((address_space(3))) void*)(l),
      16, 0, 0);
}

// ---------------------------------------------------------------------------
// elementwise fp32 -> fp16 (vectorized: float4 in, 4xfp16 out)
// ---------------------------------------------------------------------------
__global__ void convert_f32_f16_kernel(const float* __restrict__ in,
                                       half_t* __restrict__ out, int n4) {
  int i = blockIdx.x * 256 + threadIdx.x;
  if (i >= n4) return;
  const float4 v = reinterpret_cast<const float4*>(in)[i];
  f16x4 o;
  o[0] = (half_t)v.x; o[1] = (half_t)v.y; o[2] = (half_t)v.z; o[3] = (half_t)v.w;
  reinterpret_cast<f16x4*>(out)[i] = o;
}

// ---------------------------------------------------------------------------
// W [K,N] fp32 row-major  ->  Wt [N,K] fp16 row-major (LDS 32x32 tile transpose)
// ---------------------------------------------------------------------------
__global__ void wtrans_kernel(const float* __restrict__ W,
                              half_t* __restrict__ Wt, int K, int N) {
  __shared__ float tile[32][33];
  const int n0 = blockIdx.x * 32;
  const int k0 = blockIdx.y * 32;
  const int tx = threadIdx.x, ty = threadIdx.y;   // block (32,8)
#pragma unroll
  for (int r = 0; r < 32; r += 8)
    tile[ty + r][tx] = W[(size_t)(k0 + ty + r) * N + n0 + tx];
  __syncthreads();
#pragma unroll
  for (int r = 0; r < 32; r += 8)
    Wt[(size_t)(n0 + ty + r) * K + k0 + tx] = (half_t)tile[tx][ty + r];
}

// ---------------------------------------------------------------------------
// RoPE sin/cos table: tab[l*64+d] = {cos(l*invfreq(d)), sin(l*invfreq(d))}
// ---------------------------------------------------------------------------
__global__ void ropetab_kernel(float2* __restrict__ tab) {
  const int idx = blockIdx.x * 256 + threadIdx.x;   // NL*64 entries
  const int d = idx & 63;
  const int l = idx >> 6;
  const float inv_freq = exp2f(-(float)d * 0.20762050593045935f);
  const float ang = (float)l * inv_freq;
  float sn, cs;
  __sincosf(ang, &sn, &cs);
  tab[idx] = make_float2(cs, sn);
}

// ---------------------------------------------------------------------------
// GEMM (R11, best measured): 256x256 tile, 8 waves, BK=64 as 2 K-halves,
// 2 phases/K-tile, 32 MFMA/phase, one barrier + one combined vmcnt+lgkm wait
// per phase. See R11 comments for the full RAW/WAR audit.
// ---------------------------------------------------------------------------
template <typename OutT>
__global__ __launch_bounds__(512, 2) void gemm256_kernel(
    const half_t* __restrict__ A, const half_t* __restrict__ Bt,
    const float* __restrict__ B0, const float* __restrict__ B1,
    const float* __restrict__ B2, OutT* __restrict__ C,
    int M, int N, int K) {
  __shared__ __align__(16) half_t As[2][2][256 * 32];   // [buf][kh] 16KB each
  __shared__ __align__(16) half_t Bs[2][2][256 * 32];

  const int tid = threadIdx.x;
  const int wave = tid >> 6, lane = tid & 63;
  const int r16 = lane & 15, quad = lane >> 4;
  const int wm = wave >> 2, wn = wave & 3;   // 2M x 4N wave grid

  // T1: XCD-chunked swizzle of linear block id (nwg % 8 == 0 for our grids)
  const int nbx = N >> 8;
  const int lid = (int)(blockIdx.y * gridDim.x + blockIdx.x);
  const int nwg = (int)(gridDim.x * gridDim.y);
  const int cpx = nwg >> 3;
  const int swz = (lid & 7) * cpx + (lid >> 3);
  const int brow = (swz / nbx) * 256;
  const int bcol = (swz % nbx) * 256;

  const int NT = K >> 6;   // K/64 tiles

  auto stA = [&](int t, int kh) {
    const int buf = t & 1;
    const int k0 = (t << 6) + (kh << 5);
#pragma unroll
    for (int j = 0; j < 2; ++j) {
      const int s = j * 512 + wave * 64 + lane;
      const int row = s >> 2;
      const int cg = (s & 3) ^ ((row >> 1) & 3);
      gll16(A + (size_t)(brow + row) * K + k0 + cg * 8,
            &As[buf][kh][(j * 512 + wave * 64) * 8]);
    }
  };
  auto stB = [&](int t, int kh) {
    const int buf = t & 1;
    const int k0 = (t << 6) + (kh << 5);
#pragma unroll
    for (int j = 0; j < 2; ++j) {
      const int s = j * 512 + wave * 64 + lane;
      const int row = s >> 2;
      const int cg = (s & 3) ^ ((row >> 1) & 3);
      gll16(Bt + (size_t)(bcol + row) * K + k0 + cg * 8,
            &Bs[buf][kh][(j * 512 + wave * 64) * 8]);
    }
  };

  f32x4 acc[8][4] = {};
  const int csw = (quad ^ ((r16 >> 1) & 3)) << 3;   // swizzled chunk (halfs)

  stA(0, 0); stB(0, 0); stA(0, 1); stB(0, 1); stA(1, 0); stB(1, 0);
  asm volatile("s_waitcnt vmcnt(8)" ::: "memory");
  __builtin_amdgcn_s_barrier();

  for (int t = 0; t < NT; ++t) {
    const int buf = t & 1;
    const half_t* Ak0 = &As[buf][0][0];
    const half_t* Ak1 = &As[buf][1][0];
    const half_t* Bk0 = &Bs[buf][0][0];
    const half_t* Bk1 = &Bs[buf][1][0];
    f16x8 af[4], bf[4], ah[4];

    // ============ PA: kc0, 32 MFMA ============
#pragma unroll
    for (int mi = 0; mi < 4; ++mi)
      af[mi] = *reinterpret_cast<const f16x8*>(
          &Ak0[(wm * 128 + mi * 16 + r16) * 32 + csw]);
#pragma unroll
    for (int ni = 0; ni < 4; ++ni)
      bf[ni] = *reinterpret_cast<const f16x8*>(
          &Bk0[(wn * 64 + ni * 16 + r16) * 32 + csw]);
#pragma unroll
    for (int mi = 0; mi < 4; ++mi)
      ah[mi] = *reinterpret_cast<const f16x8*>(
          &Ak0[(wm * 128 + 64 + mi * 16 + r16) * 32 + csw]);
    if (t + 1 < NT) {
      stA(t + 1, 1); stB(t + 1, 1);
      asm volatile("s_waitcnt vmcnt(8) lgkmcnt(0)" ::: "memory");
    } else {
      asm volatile("s_waitcnt vmcnt(4) lgkmcnt(0)" ::: "memory");
    }
    __builtin_amdgcn_sched_barrier(0);
    __builtin_amdgcn_s_barrier();
    __builtin_amdgcn_sched_barrier(0);
    __builtin_amdgcn_s_setprio(1);
#pragma unroll
    for (int mi = 0; mi < 4; ++mi)
#pragma unroll
      for (int ni = 0; ni < 4; ++ni)
        acc[mi][ni] = __builtin_amdgcn_mfma_f32_16x16x32_f16(
            af[mi], bf[ni], acc[mi][ni], 0, 0, 0);
#pragma unroll
    for (int mi = 0; mi < 4; ++mi)
#pragma unroll
      for (int ni = 0; ni < 4; ++ni)
        acc[mi + 4][ni] = __builtin_amdgcn_mfma_f32_16x16x32_f16(
            ah[mi], bf[ni], acc[mi + 4][ni], 0, 0, 0);
    __builtin_amdgcn_s_setprio(0);

    // ============ PB: kc1, 32 MFMA ============
#pragma unroll
    for (int mi = 0; mi < 4; ++mi)
      af[mi] = *reinterpret_cast<const f16x8*>(
          &Ak1[(wm * 128 + mi * 16 + r16) * 32 + csw]);
#pragma unroll
    for (int ni = 0; ni < 4; ++ni)
      bf[ni] = *reinterpret_cast<const f16x8*>(
          &Bk1[(wn * 64 + ni * 16 + r16) * 32 + csw]);
#pragma unroll
    for (int mi = 0; mi < 4; ++mi)
      ah[mi] = *reinterpret_cast<const f16x8*>(
          &Ak1[(wm * 128 + 64 + mi * 16 + r16) * 32 + csw]);
    if (t + 2 < NT) {
      stA(t + 2, 0); stB(t + 2, 0);
      asm volatile("s_waitcnt vmcnt(8) lgkmcnt(0)" ::: "memory");
    } else if (t + 1 < NT) {
      asm volatile("s_waitcnt vmcnt(8) lgkmcnt(0)" ::: "memory");
    } else {
      asm volatile("s_waitcnt vmcnt(0) lgkmcnt(0)" ::: "memory");
    }
    __builtin_amdgcn_sched_barrier(0);
    __builtin_amdgcn_s_barrier();
    __builtin_amdgcn_sched_barrier(0);
    __builtin_amdgcn_s_setprio(1);
#pragma unroll
    for (int mi = 0; mi < 4; ++mi)
#pragma unroll
      for (int ni = 0; ni < 4; ++ni)
        acc[mi][ni] = __builtin_amdgcn_mfma_f32_16x16x32_f16(
            af[mi], bf[ni], acc[mi][ni], 0, 0, 0);
#pragma unroll
    for (int mi = 0; mi < 4; ++mi)
#pragma unroll
      for (int ni = 0; ni < 4; ++ni)
        acc[mi + 4][ni] = __builtin_amdgcn_mfma_f32_16x16x32_f16(
            ah[mi], bf[ni], acc[mi + 4][ni], 0, 0, 0);
    __builtin_amdgcn_s_setprio(0);
  }

  // epilogue: D row = (lane>>4)*4 + reg, col = lane&15 (verified C/D layout)
#pragma unroll
  for (int ni = 0; ni < 4; ++ni) {
    const int col = bcol + wn * 64 + ni * 16 + r16;
    float bv = 0.0f;
    if (B0) bv = (col < ND) ? B0[col]
                            : (col < ND + NKV * NHD ? B1[col - ND]
                                                    : B2[col - ND - NKV * NHD]);
#pragma unroll
    for (int mi = 0; mi < 8; ++mi) {
      const int row0 = brow + wm * 128 + mi * 16 + quad * 4;
#pragma unroll
      for (int i = 0; i < 4; ++i)
        C[(size_t)(row0 + i) * N + col] = (OutT)(acc[mi][ni][i] + bv);
    }
  }
}

// ---------------------------------------------------------------------------
// RoPE (half-split, table-driven) + reshape for Q and K from merged raw fp16.
// ---------------------------------------------------------------------------
__global__ void ropepack_kernel(const half_t* __restrict__ rawh,
                                const float2* __restrict__ tab,
                                half_t* __restrict__ qb,
                                half_t* __restrict__ kb) {
  const size_t idx = (size_t)blockIdx.x * 256 + threadIdx.x;
  const int d = (int)(idx & 63);
  size_t t = idx >> 6;
  const int hp = (int)(t % (NH + NKV)); t /= (NH + NKV);
  const int l = (int)(t % NL);
  const int b = (int)(t / NL);
  const bool isQ = hp < NH;
  const int col0 = isQ ? hp * NHD : ND + (hp - NH) * NHD;
  const half_t* src = rawh + ((size_t)b * NL + l) * NQKV + col0;
  const float x1 = (float)src[d];
  const float x2 = (float)src[d + 64];
  const float2 cssn = tab[(size_t)l * 64 + d];
  const float scale = isQ ? QK_SCALE : 1.0f;
  half_t* dst = isQ ? qb + ((size_t)(b * NH + hp) * NL + l) * NHD
                    : kb + ((size_t)(b * NKV + (hp - NH)) * NL + l) * NHD;
  dst[d]      = (half_t)((x1 * cssn.x - x2 * cssn.y) * scale);
  dst[d + 64] = (half_t)((x2 * cssn.x + x1 * cssn.y) * scale);
}

// ---------------------------------------------------------------------------
// V: merged raw fp16 cols [5120,6144) -> Vt [B, KV, HD, L] fp16 (transpose)
// ---------------------------------------------------------------------------
__global__ void vtrans16_kernel(const half_t* __restrict__ rawh,
                                half_t* __restrict__ Vt) {
  __shared__ half_t tile[32][34];
  const int bkv = blockIdx.z;
  const int l0 = blockIdx.x * 32;
  const int d0 = blockIdx.y * 32;
  const int b = bkv / NKV, kvh = bkv % NKV;
  const int tx = threadIdx.x, ty = threadIdx.y;   // block (32,8)
#pragma unroll
  for (int r = 0; r < 32; r += 8)
    tile[ty + r][tx] = rawh[(size_t)(b * NL + l0 + ty + r) * NQKV
                            + ND + NKV * NHD + kvh * NHD + d0 + tx];
  __syncthreads();
  half_t* dst = Vt + (size_t)bkv * NHD * NL;
#pragma unroll
  for (int r = 0; r < 32; r += 8)
    dst[(size_t)(d0 + ty + r) * NL + l0 + tx] = tile[tx][ty + r];
}

// ---------------------------------------------------------------------------
// Flash attention (non-causal, GQA). 8 waves x 32 Q-rows = 256 rows/block.
// R13: KVB=32, ring-3 K/V (3x8KB each) + 8KB P = 56KB LDS -> 2 blocks/CU
// (16 waves) with VGPR cap 128 (launch_bounds(512,2); R12's (512,4) forced
// a 64-VGPR cap -> spill). Counted vmcnt(2) at top of tile; stage(t+2)
// post-barrier (WAR safe: tile t-1's reads consumed by MFMAs before each
// wave reached this barrier; vmcnt+barrier gives block-wide RAW residency).
// Softmax: fixed ref M0, per-lane deferred row-sum, rare wave-uniform
// fallback rescale. Per-quad conflict-free swizzles. T5 setprio on MFMA.
// ---------------------------------------------------------------------------
#define KVB 32

__global__ __launch_bounds__(512, 2) void attn_kernel(
    const half_t* __restrict__ Q,   // [B,H,L,HD] scaled
    const half_t* __restrict__ Kh,  // [B,KV,L,HD]
    const half_t* __restrict__ Vt,  // [B,KV,HD,L]
    half_t* __restrict__ O) {
  __shared__ half_t Ks[3][KVB * NHD];   // 3 x 8KB
  __shared__ half_t Vs[3][NHD * KVB];   // 3 x 8KB
  __shared__ half_t Ps[8][16 * KVB];    // 8KB, per-wave P tile

  const int tid = threadIdx.x;
  const int wave = tid >> 6, lane = tid & 63;
  const int r16 = lane & 15, quad = lane >> 4;
  const int r7 = r16 & 7;

  // XCD-chunked swizzle: 64 consecutive work-items per XCD (512 = 8*64)
  const int bid = (int)blockIdx.x;
  const int swz = (bid & 7) * 64 + (bid >> 3);
  const int nqt = NL / 256;                    // 8
  const int bh = swz / nqt, qt = swz % nqt;
  const int b = bh / NH, h = bh % NH;
  const int kvh = h / NG;

  const int qrow0 = qt * 256 + wave * 32;
  const half_t* Qb = Q  + ((size_t)(b * NH + h) * NL + qrow0) * NHD;
  const half_t* Kb = Kh + ((size_t)(b * NKV + kvh) * NL) * NHD;
  const half_t* Vb = Vt + ((size_t)(b * NKV + kvh) * NHD) * NL;
  half_t* Pw = &Ps[wave][0];

  // stage tile at n0 into ring slot buf: K 512 chunks + V 512 chunks,
  // 1 chunk per thread each (2 vmcnt ops per stage per wave).
  auto stage = [&](int buf, int n0) {
    const int slot = wave * 64 + lane;
    {
      const int row = slot >> 4;                  // key row 0..31
      const int c = (slot & 15) ^ (row & 7);
      gll16(Kb + (size_t)(n0 + row) * NHD + c * 8, &Ks[buf][slot * 8]);
    }
    {
      const int row = slot >> 2;                  // d row 0..127
      const int c = (slot & 3) ^ ((row >> 1) & 3);
      gll16(Vb + (size_t)row * NL + n0 + c * 8, &Vs[buf][slot * 8]);
    }
  };

  stage(0, 0);

  // Q fragments: 2 row-tiles x 4 k-chunks (8 vmcnt ops)
  f16x8 qf[2][4];
#pragma unroll
  for (int rt = 0; rt < 2; ++rt)
#pragma unroll
    for (int c = 0; c < 4; ++c)
      qf[rt][c] = *reinterpret_cast<const f16x8*>(
          &Qb[(size_t)(rt * 16 + r16) * NHD + c * 32 + quad * 8]);

  stage(1, KVB);

  f32x4 oacc[2][8];
  float m_run[2][4], lsum[2][4];
#pragma unroll
  for (int rt = 0; rt < 2; ++rt) {
#pragma unroll
    for (int i = 0; i < 4; ++i) { m_run[rt][i] = M0; lsum[rt][i] = 0.0f; }
#pragma unroll
    for (int dt = 0; dt < 8; ++dt) oacc[rt][dt] = (f32x4){0.f, 0.f, 0.f, 0.f};
  }

  const int NT = NL / KVB;   // 64
  const int chv = (quad ^ ((r16 >> 1) & 3)) * 8;       // V read chunk
  const int chp = (quad ^ ((r16 >> 2) & 3)) * 8;       // P read chunk
  int cur = 0, stg = 2;

  for (int t = 0; t < NT; ++t) {
    // retire tile t (own share); barrier makes it block-wide
    if (t + 1 < NT) {
      asm volatile("s_waitcnt vmcnt(2)" ::: "memory");
    } else {
      asm volatile("s_waitcnt vmcnt(0)" ::: "memory");
    }
    __builtin_amdgcn_s_barrier();
    __builtin_amdgcn_sched_barrier(0);
    if (t + 2 < NT) stage(stg, (t + 2) * KVB);

    const half_t* Kc = &Ks[cur][0];
    const half_t* Vc = &Vs[cur][0];

    // ---- S = Q K^T (swizzled K reads) ----
    f32x4 s[2][2] = {};
    __builtin_amdgcn_s_setprio(1);
#pragma unroll
    for (int c = 0; c < 4; ++c) {
      const int ch = ((c * 4 + quad) ^ r7) * 8;
#pragma unroll
      for (int nt = 0; nt < 2; ++nt) {
        f16x8 kf = *reinterpret_cast<const f16x8*>(&Kc[(nt * 16 + r16) * NHD + ch]);
        s[0][nt] = __builtin_amdgcn_mfma_f32_16x16x32_f16(qf[0][c], kf, s[0][nt], 0, 0, 0);
        s[1][nt] = __builtin_amdgcn_mfma_f32_16x16x32_f16(qf[1][c], kf, s[1][nt], 0, 0, 0);
      }
    }
    __builtin_amdgcn_s_setprio(0);

    // ---- fallback check (no mx array: fold into predicate) ----
    bool need = false;
#pragma unroll
    for (int rt = 0; rt < 2; ++rt)
#pragma unroll
      for (int i = 0; i < 4; ++i)
        need = need || (fmaxf(s[rt][0][i], s[rt][1][i]) > m_run[rt][i] + THR);
    if (__any(need ? 1 : 0)) {   // rare: full reduce + rescale (correctness)
#pragma unroll
      for (int rt = 0; rt < 2; ++rt)
#pragma unroll
        for (int i = 0; i < 4; ++i) {
          float m = fmaxf(s[rt][0][i], s[rt][1][i]);
#pragma unroll
          for (int off = 1; off < 16; off <<= 1)
            m = fmaxf(m, __shfl_xor(m, off));
          const float mn = fmaxf(m_run[rt][i], m);
          const float corr = exp2f((m_run[rt][i] - mn) * RLOG2E);
          m_run[rt][i] = mn;
          lsum[rt][i] *= corr;
#pragma unroll
          for (int dt = 0; dt < 8; ++dt) oacc[rt][dt][i] *= corr;
        }
    }

    // ---- P = exp(S - m), per-lane partial sums, swizzled LDS writes ----
    f16x8 pa[2];
#pragma unroll
    for (int rt = 0; rt < 2; ++rt) {
#pragma unroll
      for (int i = 0; i < 4; ++i) {
        const float mrl = m_run[rt][i] * RLOG2E;
        const float p0 = exp2f(s[rt][0][i] * RLOG2E - mrl);
        const float p1 = exp2f(s[rt][1][i] * RLOG2E - mrl);
        lsum[rt][i] += p0 + p1;
        const int row = quad * 4 + i;
        Pw[row * KVB + (((r16 >> 3) ^ quad) * 8) + r7] = (half_t)p0;
        Pw[row * KVB + (((2 + (r16 >> 3)) ^ quad) * 8) + r7] = (half_t)p1;
      }
      // A-fragment (wave-private LDS; in-order DS pipe, no barrier)
      pa[rt] = *reinterpret_cast<const f16x8*>(&Pw[r16 * KVB + chp]);
    }

    // ---- O += P V (swizzled V reads, shared across both row-tiles) ----
    __builtin_amdgcn_s_setprio(1);
#pragma unroll
    for (int dt = 0; dt < 8; ++dt) {
      const int row = dt * 16 + r16;
      f16x8 v = *reinterpret_cast<const f16x8*>(&Vc[row * KVB + chv]);
      oacc[0][dt] = __builtin_amdgcn_mfma_f32_16x16x32_f16(pa[0], v, oacc[0][dt], 0, 0, 0);
      oacc[1][dt] = __builtin_amdgcn_mfma_f32_16x16x32_f16(pa[1], v, oacc[1][dt], 0, 0, 0);
    }
    __builtin_amdgcn_s_setprio(0);

    cur = (cur == 2) ? 0 : cur + 1;
    stg = (stg == 2) ? 0 : stg + 1;
  }

  // ---- epilogue: one deferred row-sum reduce, normalize, write fp16 ----
  half_t* Ob = O + ((size_t)(b * NL) + qrow0) * (NH * NHD) + (size_t)h * NHD;
#pragma unroll
  for (int rt = 0; rt < 2; ++rt)
#pragma unroll
    for (int i = 0; i < 4; ++i) {
      float l = lsum[rt][i];
#pragma unroll
      for (int off = 1; off < 16; off <<= 1)
        l += __shfl_xor(l, off);
      const float inv = 1.0f / l;
      const int rl = rt * 16 + quad * 4 + i;
#pragma unroll
      for (int dt = 0; dt < 8; ++dt)
        Ob[(size_t)rl * (NH * NHD) + dt * 16 + r16] =
            (half_t)(oacc[rt][dt][i] * inv);
    }
}

// ---------------------------------------------------------------------------
extern "C" void kernel_launch(void* const* d_in, const int* in_sizes, int n_in,
                              void* d_out, int out_size, void* d_ws, size_t ws_size,
                              hipStream_t stream) {
  const float* x  = (const float*)d_in[0];
  const float* Wq = (const float*)d_in[1];
  const float* bq = (const float*)d_in[2];
  const float* Wk = (const float*)d_in[3];
  const float* bk = (const float*)d_in[4];
  const float* Wv = (const float*)d_in[5];
  const float* bv = (const float*)d_in[6];
  const float* Wo = (const float*)d_in[7];
  float* out = (float*)d_out;

  char* ws = (char*)d_ws;
  size_t off = 0;
  auto alloc = [&](size_t bytes) {
    size_t cur = off;
    off += (bytes + 255) & ~(size_t)255;
    return cur;
  };
  const size_t M = (size_t)NB * NL;  // 4096 token rows
  // buffer plan (~186 MB):
  half_t* xb   = (half_t*)(ws + alloc(M * ND * 2));            // x fp16; reused as AttnOut
  half_t* wqkv = (half_t*)(ws + alloc((size_t)NQKV * ND * 2)); // [Wq;Wk;Wv]^T; reused for Wo^T
  half_t* rawh = (half_t*)(ws + alloc(M * NQKV * 2));          // merged QKV raw fp16
  half_t* qb   = (half_t*)(ws + alloc(M * (size_t)(NH * NHD) * 2));
  half_t* kb   = (half_t*)(ws + alloc(M * (size_t)(NKV * NHD) * 2));
  half_t* vt   = (half_t*)(ws + alloc(M * (size_t)(NKV * NHD) * 2));
  float2* tab  = (float2*)(ws + alloc((size_t)NL * 64 * 8));   // RoPE cos/sin

  // 1) x -> fp16 ; RoPE table
  {
    int n4 = (int)(M * ND / 4);
    convert_f32_f16_kernel<<<dim3((n4 + 255) / 256), dim3(256), 0, stream>>>(x, xb, n4);
  }
  ropetab_kernel<<<dim3(NL * 64 / 256), dim3(256), 0, stream>>>(tab);

  // 2) weight transposes into merged [6144][4096] fp16
  wtrans_kernel<<<dim3(ND / 32, ND / 32), dim3(32, 8), 0, stream>>>(
      Wq, wqkv, ND, ND);
  wtrans_kernel<<<dim3((NKV * NHD) / 32, ND / 32), dim3(32, 8), 0, stream>>>(
      Wk, wqkv + (size_t)ND * ND, ND, NKV * NHD);
  wtrans_kernel<<<dim3((NKV * NHD) / 32, ND / 32), dim3(32, 8), 0, stream>>>(
      Wv, wqkv + (size_t)(ND + NKV * NHD) * ND, ND, NKV * NHD);

  // 3) merged QKV GEMM -> rawh fp16 (bias fused, 3-way select)
  gemm256_kernel<half_t><<<dim3(NQKV / 256, M / 256), dim3(512), 0, stream>>>(
      xb, wqkv, bq, bk, bv, rawh, (int)M, NQKV, ND);

  // 4) RoPE+pack Q,K (table-driven); transpose V
  ropepack_kernel<<<dim3((unsigned)(M * (NH + NKV) * 64 / 256)), dim3(256), 0, stream>>>(
      rawh, tab, qb, kb);
  vtrans16_kernel<<<dim3(NL / 32, NHD / 32, NB * NKV), dim3(32, 8), 0, stream>>>(rawh, vt);

  // 5) Wo^T into wqkv (dead after step 3; stream order guarantees safety)
  wtrans_kernel<<<dim3(ND / 32, ND / 32), dim3(32, 8), 0, stream>>>(Wo, wqkv, NH * NHD, ND);

  // 6) attention -> xb (reused as AttnOut, [B*L, H*HD] fp16)
  attn_kernel<<<dim3(NB * NH * (NL / 256)), dim3(512), 0, stream>>>(qb, kb, vt, xb);

  // 7) output projection -> d_out (fp32)
  gemm256_kernel<float><<<dim3(ND / 256, M / 256), dim3(512), 0, stream>>>(
      xb, wqkv, nullptr, nullptr, nullptr, out, (int)M, ND, ND);
}

// Round 14
// 648.414 us; speedup vs baseline: 1.3797x; 1.0432x over previous
//
#include <hip/hip_runtime.h>
#include <stdint.h>
#include <stddef.h>

// ---------------------------------------------------------------------------
// Fused GQA attention block: QKV proj + half-split RoPE + flash attention +
// output proj. fp16 MFMA (16x16x32) everywhere, fp32 accumulate/softmax.
// R14: full revert to the R11 configuration (best measured, 647us).
// R12/R13 post-mortem: 2 blocks/CU for attn is structurally infeasible
// (oacc AGPRs + VGPRs ~164/wave -> 12 waves/CU < 16 needed); KVB=32 doubled
// sync count and lost 12%. attn restored to KVB=64 / 80KB / setprio (229us).
// GEMM: R11 2-phase counted-vmcnt schedule (230us QKV, MfmaUtil 40%).
// ---------------------------------------------------------------------------

typedef _Float16 half_t;
typedef __attribute__((ext_vector_type(4))) _Float16 f16x4;
typedef __attribute__((ext_vector_type(8))) _Float16 f16x8;
typedef __attribute__((ext_vector_type(4))) float f32x4;

#define NB 2
#define NL 2048
#define ND 4096
#define NH 32
#define NKV 8
#define NHD 128
#define NG 4               // H / KV
#define NQKV 6144          // H*HD + 2*KV*HD
#define QK_SCALE 0.08838834764831845f   // HD^-0.5
#define RLOG2E 1.4426950408889634f
#define M0 6.0f            // fixed softmax reference (scores ~N(0,1.64^2))
#define THR 8.0f           // defer-max threshold (fallback if mx > M0+THR)

// async global->LDS, 16B per lane. LDS dest must be wave-uniform base;
// lane i lands at base + i*16 (HW-defined linear scatter).
static __device__ __forceinline__ void gll16(const void* g, void* l) {
  __builtin_amdgcn_global_load_lds(
      (__attribute__((address_space(1))) void*)(void*)(g),
      (__attribute__((address_space(3))) void*)(l),
      16, 0, 0);
}

// ---------------------------------------------------------------------------
// elementwise fp32 -> fp16 (vectorized: float4 in, 4xfp16 out)
// ---------------------------------------------------------------------------
__global__ void convert_f32_f16_kernel(const float* __restrict__ in,
                                       half_t* __restrict__ out, int n4) {
  int i = blockIdx.x * 256 + threadIdx.x;
  if (i >= n4) return;
  const float4 v = reinterpret_cast<const float4*>(in)[i];
  f16x4 o;
  o[0] = (half_t)v.x; o[1] = (half_t)v.y; o[2] = (half_t)v.z; o[3] = (half_t)v.w;
  reinterpret_cast<f16x4*>(out)[i] = o;
}

// ---------------------------------------------------------------------------
// W [K,N] fp32 row-major  ->  Wt [N,K] fp16 row-major (LDS 32x32 tile transpose)
// ---------------------------------------------------------------------------
__global__ void wtrans_kernel(const float* __restrict__ W,
                              half_t* __restrict__ Wt, int K, int N) {
  __shared__ float tile[32][33];
  const int n0 = blockIdx.x * 32;
  const int k0 = blockIdx.y * 32;
  const int tx = threadIdx.x, ty = threadIdx.y;   // block (32,8)
#pragma unroll
  for (int r = 0; r < 32; r += 8)
    tile[ty + r][tx] = W[(size_t)(k0 + ty + r) * N + n0 + tx];
  __syncthreads();
#pragma unroll
  for (int r = 0; r < 32; r += 8)
    Wt[(size_t)(n0 + ty + r) * K + k0 + tx] = (half_t)tile[tx][ty + r];
}

// ---------------------------------------------------------------------------
// RoPE sin/cos table: tab[l*64+d] = {cos(l*invfreq(d)), sin(l*invfreq(d))}
// ---------------------------------------------------------------------------
__global__ void ropetab_kernel(float2* __restrict__ tab) {
  const int idx = blockIdx.x * 256 + threadIdx.x;   // NL*64 entries
  const int d = idx & 63;
  const int l = idx >> 6;
  const float inv_freq = exp2f(-(float)d * 0.20762050593045935f);
  const float ang = (float)l * inv_freq;
  float sn, cs;
  __sincosf(ang, &sn, &cs);
  tab[idx] = make_float2(cs, sn);
}

// ---------------------------------------------------------------------------
// GEMM (R11, best measured): 256x256 tile, 8 waves, BK=64 as 2 K-halves,
// 2 phases/K-tile, 32 MFMA/phase, one barrier + one combined vmcnt+lgkm wait
// per phase.
// RAW: (t)k0 retired by PB(t-1)'s vmcnt(8)+barrier; (t)k1 by PA(t)'s
// vmcnt(8)+barrier. WAR: lgkm0 BEFORE each barrier pins every wave's reads;
// the slot staged in the next phase cannot race them.
// Swizzle: global chunk cg at LDS chunk cg^((row>>1)&3); reads use
// csw = (quad ^ ((r16>>1)&3)) -> measured 0 bank conflicts.
// ---------------------------------------------------------------------------
template <typename OutT>
__global__ __launch_bounds__(512, 2) void gemm256_kernel(
    const half_t* __restrict__ A, const half_t* __restrict__ Bt,
    const float* __restrict__ B0, const float* __restrict__ B1,
    const float* __restrict__ B2, OutT* __restrict__ C,
    int M, int N, int K) {
  __shared__ __align__(16) half_t As[2][2][256 * 32];   // [buf][kh] 16KB each
  __shared__ __align__(16) half_t Bs[2][2][256 * 32];

  const int tid = threadIdx.x;
  const int wave = tid >> 6, lane = tid & 63;
  const int r16 = lane & 15, quad = lane >> 4;
  const int wm = wave >> 2, wn = wave & 3;   // 2M x 4N wave grid

  // T1: XCD-chunked swizzle of linear block id (nwg % 8 == 0 for our grids)
  const int nbx = N >> 8;
  const int lid = (int)(blockIdx.y * gridDim.x + blockIdx.x);
  const int nwg = (int)(gridDim.x * gridDim.y);
  const int cpx = nwg >> 3;
  const int swz = (lid & 7) * cpx + (lid >> 3);
  const int brow = (swz / nbx) * 256;
  const int bcol = (swz % nbx) * 256;

  const int NT = K >> 6;   // K/64 tiles

  auto stA = [&](int t, int kh) {
    const int buf = t & 1;
    const int k0 = (t << 6) + (kh << 5);
#pragma unroll
    for (int j = 0; j < 2; ++j) {
      const int s = j * 512 + wave * 64 + lane;
      const int row = s >> 2;
      const int cg = (s & 3) ^ ((row >> 1) & 3);
      gll16(A + (size_t)(brow + row) * K + k0 + cg * 8,
            &As[buf][kh][(j * 512 + wave * 64) * 8]);
    }
  };
  auto stB = [&](int t, int kh) {
    const int buf = t & 1;
    const int k0 = (t << 6) + (kh << 5);
#pragma unroll
    for (int j = 0; j < 2; ++j) {
      const int s = j * 512 + wave * 64 + lane;
      const int row = s >> 2;
      const int cg = (s & 3) ^ ((row >> 1) & 3);
      gll16(Bt + (size_t)(bcol + row) * K + k0 + cg * 8,
            &Bs[buf][kh][(j * 512 + wave * 64) * 8]);
    }
  };

  f32x4 acc[8][4] = {};
  const int csw = (quad ^ ((r16 >> 1) & 3)) << 3;   // swizzled chunk (halfs)

  stA(0, 0); stB(0, 0); stA(0, 1); stB(0, 1); stA(1, 0); stB(1, 0);
  asm volatile("s_waitcnt vmcnt(8)" ::: "memory");
  __builtin_amdgcn_s_barrier();

  for (int t = 0; t < NT; ++t) {
    const int buf = t & 1;
    const half_t* Ak0 = &As[buf][0][0];
    const half_t* Ak1 = &As[buf][1][0];
    const half_t* Bk0 = &Bs[buf][0][0];
    const half_t* Bk1 = &Bs[buf][1][0];
    f16x8 af[4], bf[4], ah[4];

    // ============ PA: kc0, 32 MFMA ============
#pragma unroll
    for (int mi = 0; mi < 4; ++mi)
      af[mi] = *reinterpret_cast<const f16x8*>(
          &Ak0[(wm * 128 + mi * 16 + r16) * 32 + csw]);
#pragma unroll
    for (int ni = 0; ni < 4; ++ni)
      bf[ni] = *reinterpret_cast<const f16x8*>(
          &Bk0[(wn * 64 + ni * 16 + r16) * 32 + csw]);
#pragma unroll
    for (int mi = 0; mi < 4; ++mi)
      ah[mi] = *reinterpret_cast<const f16x8*>(
          &Ak0[(wm * 128 + 64 + mi * 16 + r16) * 32 + csw]);
    if (t + 1 < NT) {
      stA(t + 1, 1); stB(t + 1, 1);
      asm volatile("s_waitcnt vmcnt(8) lgkmcnt(0)" ::: "memory");
    } else {
      asm volatile("s_waitcnt vmcnt(4) lgkmcnt(0)" ::: "memory");
    }
    __builtin_amdgcn_sched_barrier(0);
    __builtin_amdgcn_s_barrier();
    __builtin_amdgcn_sched_barrier(0);
    __builtin_amdgcn_s_setprio(1);
#pragma unroll
    for (int mi = 0; mi < 4; ++mi)
#pragma unroll
      for (int ni = 0; ni < 4; ++ni)
        acc[mi][ni] = __builtin_amdgcn_mfma_f32_16x16x32_f16(
            af[mi], bf[ni], acc[mi][ni], 0, 0, 0);
#pragma unroll
    for (int mi = 0; mi < 4; ++mi)
#pragma unroll
      for (int ni = 0; ni < 4; ++ni)
        acc[mi + 4][ni] = __builtin_amdgcn_mfma_f32_16x16x32_f16(
            ah[mi], bf[ni], acc[mi + 4][ni], 0, 0, 0);
    __builtin_amdgcn_s_setprio(0);

    // ============ PB: kc1, 32 MFMA ============
#pragma unroll
    for (int mi = 0; mi < 4; ++mi)
      af[mi] = *reinterpret_cast<const f16x8*>(
          &Ak1[(wm * 128 + mi * 16 + r16) * 32 + csw]);
#pragma unroll
    for (int ni = 0; ni < 4; ++ni)
      bf[ni] = *reinterpret_cast<const f16x8*>(
          &Bk1[(wn * 64 + ni * 16 + r16) * 32 + csw]);
#pragma unroll
    for (int mi = 0; mi < 4; ++mi)
      ah[mi] = *reinterpret_cast<const f16x8*>(
          &Ak1[(wm * 128 + 64 + mi * 16 + r16) * 32 + csw]);
    if (t + 2 < NT) {
      stA(t + 2, 0); stB(t + 2, 0);
      asm volatile("s_waitcnt vmcnt(8) lgkmcnt(0)" ::: "memory");
    } else if (t + 1 < NT) {
      asm volatile("s_waitcnt vmcnt(8) lgkmcnt(0)" ::: "memory");
    } else {
      asm volatile("s_waitcnt vmcnt(0) lgkmcnt(0)" ::: "memory");
    }
    __builtin_amdgcn_sched_barrier(0);
    __builtin_amdgcn_s_barrier();
    __builtin_amdgcn_sched_barrier(0);
    __builtin_amdgcn_s_setprio(1);
#pragma unroll
    for (int mi = 0; mi < 4; ++mi)
#pragma unroll
      for (int ni = 0; ni < 4; ++ni)
        acc[mi][ni] = __builtin_amdgcn_mfma_f32_16x16x32_f16(
            af[mi], bf[ni], acc[mi][ni], 0, 0, 0);
#pragma unroll
    for (int mi = 0; mi < 4; ++mi)
#pragma unroll
      for (int ni = 0; ni < 4; ++ni)
        acc[mi + 4][ni] = __builtin_amdgcn_mfma_f32_16x16x32_f16(
            ah[mi], bf[ni], acc[mi + 4][ni], 0, 0, 0);
    __builtin_amdgcn_s_setprio(0);
  }

  // epilogue: D row = (lane>>4)*4 + reg, col = lane&15 (verified C/D layout)
#pragma unroll
  for (int ni = 0; ni < 4; ++ni) {
    const int col = bcol + wn * 64 + ni * 16 + r16;
    float bv = 0.0f;
    if (B0) bv = (col < ND) ? B0[col]
                            : (col < ND + NKV * NHD ? B1[col - ND]
                                                    : B2[col - ND - NKV * NHD]);
#pragma unroll
    for (int mi = 0; mi < 8; ++mi) {
      const int row0 = brow + wm * 128 + mi * 16 + quad * 4;
#pragma unroll
      for (int i = 0; i < 4; ++i)
        C[(size_t)(row0 + i) * N + col] = (OutT)(acc[mi][ni][i] + bv);
    }
  }
}

// ---------------------------------------------------------------------------
// RoPE (half-split, table-driven) + reshape for Q and K from merged raw fp16.
// ---------------------------------------------------------------------------
__global__ void ropepack_kernel(const half_t* __restrict__ rawh,
                                const float2* __restrict__ tab,
                                half_t* __restrict__ qb,
                                half_t* __restrict__ kb) {
  const size_t idx = (size_t)blockIdx.x * 256 + threadIdx.x;
  const int d = (int)(idx & 63);
  size_t t = idx >> 6;
  const int hp = (int)(t % (NH + NKV)); t /= (NH + NKV);
  const int l = (int)(t % NL);
  const int b = (int)(t / NL);
  const bool isQ = hp < NH;
  const int col0 = isQ ? hp * NHD : ND + (hp - NH) * NHD;
  const half_t* src = rawh + ((size_t)b * NL + l) * NQKV + col0;
  const float x1 = (float)src[d];
  const float x2 = (float)src[d + 64];
  const float2 cssn = tab[(size_t)l * 64 + d];
  const float scale = isQ ? QK_SCALE : 1.0f;
  half_t* dst = isQ ? qb + ((size_t)(b * NH + hp) * NL + l) * NHD
                    : kb + ((size_t)(b * NKV + (hp - NH)) * NL + l) * NHD;
  dst[d]      = (half_t)((x1 * cssn.x - x2 * cssn.y) * scale);
  dst[d + 64] = (half_t)((x2 * cssn.x + x1 * cssn.y) * scale);
}

// ---------------------------------------------------------------------------
// V: merged raw fp16 cols [5120,6144) -> Vt [B, KV, HD, L] fp16 (transpose)
// ---------------------------------------------------------------------------
__global__ void vtrans16_kernel(const half_t* __restrict__ rawh,
                                half_t* __restrict__ Vt) {
  __shared__ half_t tile[32][34];
  const int bkv = blockIdx.z;
  const int l0 = blockIdx.x * 32;
  const int d0 = blockIdx.y * 32;
  const int b = bkv / NKV, kvh = bkv % NKV;
  const int tx = threadIdx.x, ty = threadIdx.y;   // block (32,8)
#pragma unroll
  for (int r = 0; r < 32; r += 8)
    tile[ty + r][tx] = rawh[(size_t)(b * NL + l0 + ty + r) * NQKV
                            + ND + NKV * NHD + kvh * NHD + d0 + tx];
  __syncthreads();
  half_t* dst = Vt + (size_t)bkv * NHD * NL;
#pragma unroll
  for (int r = 0; r < 32; r += 8)
    dst[(size_t)(d0 + ty + r) * NL + l0 + tx] = tile[tx][ty + r];
}

// ---------------------------------------------------------------------------
// Flash attention (non-causal, GQA). 8 waves x 32 Q-rows = 256 rows/block.
// R11 version (best measured, 229us): KVB=64, K/V double-buffered in LDS
// (80KB), XOR chunk-swizzled, fixed-ref M0 softmax with per-lane deferred
// row-sum + rare wave-uniform fallback rescale, T5 setprio on MFMA clusters.
// ---------------------------------------------------------------------------
#define KVB 64

__global__ __launch_bounds__(512, 2) void attn_kernel(
    const half_t* __restrict__ Q,   // [B,H,L,HD] scaled
    const half_t* __restrict__ Kh,  // [B,KV,L,HD]
    const half_t* __restrict__ Vt,  // [B,KV,HD,L]
    half_t* __restrict__ O) {
  __shared__ half_t Ks[2][KVB * NHD];   // 2 x 16KB
  __shared__ half_t Vs[2][NHD * KVB];   // 2 x 16KB
  __shared__ half_t Ps[8][16 * 64];     // 16KB, per-wave P tile

  const int tid = threadIdx.x;
  const int wave = tid >> 6, lane = tid & 63;
  const int r16 = lane & 15, quad = lane >> 4;
  const int r7 = r16 & 7;

  // XCD-chunked swizzle: 64 consecutive work-items per XCD (512 = 8*64)
  const int bid = (int)blockIdx.x;
  const int swz = (bid & 7) * 64 + (bid >> 3);
  const int nqt = NL / 256;                    // 8
  const int bh = swz / nqt, qt = swz % nqt;
  const int b = bh / NH, h = bh % NH;
  const int kvh = h / NG;

  const int qrow0 = qt * 256 + wave * 32;
  const half_t* Qb = Q  + ((size_t)(b * NH + h) * NL + qrow0) * NHD;
  const half_t* Kb = Kh + ((size_t)(b * NKV + kvh) * NL) * NHD;
  const half_t* Vb = Vt + ((size_t)(b * NKV + kvh) * NHD) * NL;
  half_t* Pw = &Ps[wave][0];

  // ---- stage(buf, n0): K tile 1024 slots, V tile 1024 slots (16B each) ----
  auto stage = [&](int buf, int n0) {
#pragma unroll
    for (int j = 0; j < 2; ++j) {
      const int slot = j * 512 + wave * 64 + lane;
      {
        const int row = slot >> 4;                    // key row 0..63
        const int c = (slot & 15) ^ (row & 7);        // global chunk
        gll16(Kb + (size_t)(n0 + row) * NHD + c * 8,
              &Ks[buf][(j * 512 + wave * 64) * 8]);
      }
      {
        const int row = slot >> 3;                    // d row 0..127
        const int c = (slot & 7) ^ (row & 7);
        gll16(Vb + (size_t)row * NL + n0 + c * 8,
              &Vs[buf][(j * 512 + wave * 64) * 8]);
      }
    }
  };

  stage(0, 0);

  // Q fragments: 2 row-tiles x 4 k-chunks
  f16x8 qf[2][4];
#pragma unroll
  for (int rt = 0; rt < 2; ++rt)
#pragma unroll
    for (int c = 0; c < 4; ++c)
      qf[rt][c] = *reinterpret_cast<const f16x8*>(
          &Qb[(size_t)(rt * 16 + r16) * NHD + c * 32 + quad * 8]);

  f32x4 oacc[2][8];
  float m_run[2][4], lsum[2][4];
#pragma unroll
  for (int rt = 0; rt < 2; ++rt) {
#pragma unroll
    for (int i = 0; i < 4; ++i) { m_run[rt][i] = M0; lsum[rt][i] = 0.0f; }
#pragma unroll
    for (int dt = 0; dt < 8; ++dt) oacc[rt][dt] = (f32x4){0.f, 0.f, 0.f, 0.f};
  }

  // P read swizzle (row = r16): mask = (r16&7) ^ ((r16>>3)*5)
  const int swzread = r7 ^ ((r16 >> 3) * 5);

  asm volatile("s_waitcnt vmcnt(0)" ::: "memory");
  __syncthreads();

  int cur = 0;
  for (int t = 0; t < NL / KVB; ++t, cur ^= 1) {
    if (t + 1 < NL / KVB) stage(cur ^ 1, (t + 1) * KVB);

    const half_t* Kc = &Ks[cur][0];
    const half_t* Vc = &Vs[cur][0];

    // ---- S = Q K^T (swizzled K reads) ----
    f32x4 s[2][4] = {};
    __builtin_amdgcn_s_setprio(1);
#pragma unroll
    for (int c = 0; c < 4; ++c) {
      const int ch = ((c * 4 + quad) ^ r7) * 8;
#pragma unroll
      for (int nt = 0; nt < 4; ++nt) {
        f16x8 kf = *reinterpret_cast<const f16x8*>(&Kc[(nt * 16 + r16) * NHD + ch]);
        s[0][nt] = __builtin_amdgcn_mfma_f32_16x16x32_f16(qf[0][c], kf, s[0][nt], 0, 0, 0);
        s[1][nt] = __builtin_amdgcn_mfma_f32_16x16x32_f16(qf[1][c], kf, s[1][nt], 0, 0, 0);
      }
    }
    __builtin_amdgcn_s_setprio(0);

    // ---- fallback check: any lane-local score above running ref? ----
    float mx[2][4];
    bool need = false;
#pragma unroll
    for (int rt = 0; rt < 2; ++rt)
#pragma unroll
      for (int i = 0; i < 4; ++i) {
        mx[rt][i] = fmaxf(fmaxf(s[rt][0][i], s[rt][1][i]),
                          fmaxf(s[rt][2][i], s[rt][3][i]));
        need = need || (mx[rt][i] > m_run[rt][i] + THR);
      }
    if (__any(need ? 1 : 0)) {   // rare: full reduce + rescale (correctness)
#pragma unroll
      for (int rt = 0; rt < 2; ++rt)
#pragma unroll
        for (int i = 0; i < 4; ++i) {
          float m = mx[rt][i];
#pragma unroll
          for (int off = 1; off < 16; off <<= 1)
            m = fmaxf(m, __shfl_xor(m, off));
          const float mn = fmaxf(m_run[rt][i], m);
          const float corr = exp2f((m_run[rt][i] - mn) * RLOG2E);
          m_run[rt][i] = mn;
          lsum[rt][i] *= corr;
#pragma unroll
          for (int dt = 0; dt < 8; ++dt) oacc[rt][dt][i] *= corr;
        }
    }

    // ---- P = exp(S - m), per-lane partial sums, swizzled LDS writes ----
    f16x8 pa[2][2];
#pragma unroll
    for (int rt = 0; rt < 2; ++rt) {
#pragma unroll
      for (int i = 0; i < 4; ++i) {
        const float mrl = m_run[rt][i] * RLOG2E;
        float p[4];
#pragma unroll
        for (int nt = 0; nt < 4; ++nt)
          p[nt] = exp2f(s[rt][nt][i] * RLOG2E - mrl);
        lsum[rt][i] += (p[0] + p[1]) + (p[2] + p[3]);
        const int row = quad * 4 + i;
        const int swzr = (row & 7) ^ ((row >> 3) * 5);
#pragma unroll
        for (int nt = 0; nt < 4; ++nt)
          Pw[row * 64 + (((nt * 2 + (r16 >> 3)) ^ swzr) * 8) + r7] = (half_t)p[nt];
      }
      // A-fragments (wave-private LDS; in-order DS pipe, no barrier)
      pa[rt][0] = *reinterpret_cast<const f16x8*>(&Pw[r16 * 64 + ((quad ^ swzread) * 8)]);
      pa[rt][1] = *reinterpret_cast<const f16x8*>(&Pw[r16 * 64 + (((4 + quad) ^ swzread) * 8)]);
    }

    // ---- O += P V (swizzled V reads, shared across both row-tiles) ----
    const int ch0 = (quad ^ r7) * 8;
    const int ch1 = ((4 + quad) ^ r7) * 8;
    __builtin_amdgcn_s_setprio(1);
#pragma unroll
    for (int dt = 0; dt < 8; ++dt) {
      const int row = dt * 16 + r16;
      f16x8 v0 = *reinterpret_cast<const f16x8*>(&Vc[row * 64 + ch0]);
      f16x8 v1 = *reinterpret_cast<const f16x8*>(&Vc[row * 64 + ch1]);
      oacc[0][dt] = __builtin_amdgcn_mfma_f32_16x16x32_f16(pa[0][0], v0, oacc[0][dt], 0, 0, 0);
      oacc[0][dt] = __builtin_amdgcn_mfma_f32_16x16x32_f16(pa[0][1], v1, oacc[0][dt], 0, 0, 0);
      oacc[1][dt] = __builtin_amdgcn_mfma_f32_16x16x32_f16(pa[1][0], v0, oacc[1][dt], 0, 0, 0);
      oacc[1][dt] = __builtin_amdgcn_mfma_f32_16x16x32_f16(pa[1][1], v1, oacc[1][dt], 0, 0, 0);
    }
    __builtin_amdgcn_s_setprio(0);

    asm volatile("s_waitcnt vmcnt(0)" ::: "memory");
    __syncthreads();
  }

  // ---- epilogue: one deferred row-sum reduce, normalize, write fp16 ----
  half_t* Ob = O + ((size_t)(b * NL) + qrow0) * (NH * NHD) + (size_t)h * NHD;
#pragma unroll
  for (int rt = 0; rt < 2; ++rt)
#pragma unroll
    for (int i = 0; i < 4; ++i) {
      float l = lsum[rt][i];
#pragma unroll
      for (int off = 1; off < 16; off <<= 1)
        l += __shfl_xor(l, off);
      const float inv = 1.0f / l;
      const int rl = rt * 16 + quad * 4 + i;
#pragma unroll
      for (int dt = 0; dt < 8; ++dt)
        Ob[(size_t)rl * (NH * NHD) + dt * 16 + r16] =
            (half_t)(oacc[rt][dt][i] * inv);
    }
}

// ---------------------------------------------------------------------------
extern "C" void kernel_launch(void* const* d_in, const int* in_sizes, int n_in,
                              void* d_out, int out_size, void* d_ws, size_t ws_size,
                              hipStream_t stream) {
  const float* x  = (const float*)d_in[0];
  const float* Wq = (const float*)d_in[1];
  const float* bq = (const float*)d_in[2];
  const float* Wk = (const float*)d_in[3];
  const float* bk = (const float*)d_in[4];
  const float* Wv = (const float*)d_in[5];
  const float* bv = (const float*)d_in[6];
  const float* Wo = (const float*)d_in[7];
  float* out = (float*)d_out;

  char* ws = (char*)d_ws;
  size_t off = 0;
  auto alloc = [&](size_t bytes) {
    size_t cur = off;
    off += (bytes + 255) & ~(size_t)255;
    return cur;
  };
  const size_t M = (size_t)NB * NL;  // 4096 token rows
  // buffer plan (~186 MB):
  half_t* xb   = (half_t*)(ws + alloc(M * ND * 2));            // x fp16; reused as AttnOut
  half_t* wqkv = (half_t*)(ws + alloc((size_t)NQKV * ND * 2)); // [Wq;Wk;Wv]^T; reused for Wo^T
  half_t* rawh = (half_t*)(ws + alloc(M * NQKV * 2));          // merged QKV raw fp16
  half_t* qb   = (half_t*)(ws + alloc(M * (size_t)(NH * NHD) * 2));
  half_t* kb   = (half_t*)(ws + alloc(M * (size_t)(NKV * NHD) * 2));
  half_t* vt   = (half_t*)(ws + alloc(M * (size_t)(NKV * NHD) * 2));
  float2* tab  = (float2*)(ws + alloc((size_t)NL * 64 * 8));   // RoPE cos/sin

  // 1) x -> fp16 ; RoPE table
  {
    int n4 = (int)(M * ND / 4);
    convert_f32_f16_kernel<<<dim3((n4 + 255) / 256), dim3(256), 0, stream>>>(x, xb, n4);
  }
  ropetab_kernel<<<dim3(NL * 64 / 256), dim3(256), 0, stream>>>(tab);

  // 2) weight transposes into merged [6144][4096] fp16
  wtrans_kernel<<<dim3(ND / 32, ND / 32), dim3(32, 8), 0, stream>>>(
      Wq, wqkv, ND, ND);
  wtrans_kernel<<<dim3((NKV * NHD) / 32, ND / 32), dim3(32, 8), 0, stream>>>(
      Wk, wqkv + (size_t)ND * ND, ND, NKV * NHD);
  wtrans_kernel<<<dim3((NKV * NHD) / 32, ND / 32), dim3(32, 8), 0, stream>>>(
      Wv, wqkv + (size_t)(ND + NKV * NHD) * ND, ND, NKV * NHD);

  // 3) merged QKV GEMM -> rawh fp16 (bias fused, 3-way select)
  gemm256_kernel<half_t><<<dim3(NQKV / 256, M / 256), dim3(512), 0, stream>>>(
      xb, wqkv, bq, bk, bv, rawh, (int)M, NQKV, ND);

  // 4) RoPE+pack Q,K (table-driven); transpose V
  ropepack_kernel<<<dim3((unsigned)(M * (NH + NKV) * 64 / 256)), dim3(256), 0, stream>>>(
      rawh, tab, qb, kb);
  vtrans16_kernel<<<dim3(NL / 32, NHD / 32, NB * NKV), dim3(32, 8), 0, stream>>>(rawh, vt);

  // 5) Wo^T into wqkv (dead after step 3; stream order guarantees safety)
  wtrans_kernel<<<dim3(ND / 32, ND / 32), dim3(32, 8), 0, stream>>>(Wo, wqkv, NH * NHD, ND);

  // 6) attention -> xb (reused as AttnOut, [B*L, H*HD] fp16)
  attn_kernel<<<dim3(NB * NH * (NL / 256)), dim3(512), 0, stream>>>(qb, kb, vt, xb);

  // 7) output projection -> d_out (fp32)
  gemm256_kernel<float><<<dim3(ND / 256, M / 256), dim3(512), 0, stream>>>(
      xb, wqkv, nullptr, nullptr, nullptr, out, (int)M, ND, ND);
}

// Round 15
// 639.508 us; speedup vs baseline: 1.3989x; 1.0139x over previous
//
#include <hip/hip_runtime.h>
#include <stdint.h>
#include <stddef.h>

// ---------------------------------------------------------------------------
// Fused GQA attention block: QKV proj + half-split RoPE + flash attention +
// output proj. fp16 MFMA (16x16x32) everywhere, fp32 accumulate/softmax.
// R15: R14 (verified best, 648us) + vectorized ropepack (4 d-values/thread,
// 8B loads/stores, 4x fewer threads — G13). All else byte-identical.
// Schedule-space record: GEMM 2-phase/lgkm0-before-barrier (R11) is the
// measured optimum (40% MfmaUtil; 1-barrier=25%, 8-barrier=34.5%,
// reg-pipeline=29%). Attn 2-blocks/CU infeasible (164 regs/wave).
// ---------------------------------------------------------------------------

typedef _Float16 half_t;
typedef __attribute__((ext_vector_type(4))) _Float16 f16x4;
typedef __attribute__((ext_vector_type(8))) _Float16 f16x8;
typedef __attribute__((ext_vector_type(4))) float f32x4;

#define NB 2
#define NL 2048
#define ND 4096
#define NH 32
#define NKV 8
#define NHD 128
#define NG 4               // H / KV
#define NQKV 6144          // H*HD + 2*KV*HD
#define QK_SCALE 0.08838834764831845f   // HD^-0.5
#define RLOG2E 1.4426950408889634f
#define M0 6.0f            // fixed softmax reference (scores ~N(0,1.64^2))
#define THR 8.0f           // defer-max threshold (fallback if mx > M0+THR)

// async global->LDS, 16B per lane. LDS dest must be wave-uniform base;
// lane i lands at base + i*16 (HW-defined linear scatter).
static __device__ __forceinline__ void gll16(const void* g, void* l) {
  __builtin_amdgcn_global_load_lds(
      (__attribute__((address_space(1))) void*)(void*)(g),
      (__attribute__((address_space(3))) void*)(l),
      16, 0, 0);
}

// ---------------------------------------------------------------------------
// elementwise fp32 -> fp16 (vectorized: float4 in, 4xfp16 out)
// ---------------------------------------------------------------------------
__global__ void convert_f32_f16_kernel(const float* __restrict__ in,
                                       half_t* __restrict__ out, int n4) {
  int i = blockIdx.x * 256 + threadIdx.x;
  if (i >= n4) return;
  const float4 v = reinterpret_cast<const float4*>(in)[i];
  f16x4 o;
  o[0] = (half_t)v.x; o[1] = (half_t)v.y; o[2] = (half_t)v.z; o[3] = (half_t)v.w;
  reinterpret_cast<f16x4*>(out)[i] = o;
}

// ---------------------------------------------------------------------------
// W [K,N] fp32 row-major  ->  Wt [N,K] fp16 row-major (LDS 32x32 tile transpose)
// ---------------------------------------------------------------------------
__global__ void wtrans_kernel(const float* __restrict__ W,
                              half_t* __restrict__ Wt, int K, int N) {
  __shared__ float tile[32][33];
  const int n0 = blockIdx.x * 32;
  const int k0 = blockIdx.y * 32;
  const int tx = threadIdx.x, ty = threadIdx.y;   // block (32,8)
#pragma unroll
  for (int r = 0; r < 32; r += 8)
    tile[ty + r][tx] = W[(size_t)(k0 + ty + r) * N + n0 + tx];
  __syncthreads();
#pragma unroll
  for (int r = 0; r < 32; r += 8)
    Wt[(size_t)(n0 + ty + r) * K + k0 + tx] = (half_t)tile[tx][ty + r];
}

// ---------------------------------------------------------------------------
// RoPE sin/cos table: tab[l*64+d] = {cos(l*invfreq(d)), sin(l*invfreq(d))}
// ---------------------------------------------------------------------------
__global__ void ropetab_kernel(float2* __restrict__ tab) {
  const int idx = blockIdx.x * 256 + threadIdx.x;   // NL*64 entries
  const int d = idx & 63;
  const int l = idx >> 6;
  const float inv_freq = exp2f(-(float)d * 0.20762050593045935f);
  const float ang = (float)l * inv_freq;
  float sn, cs;
  __sincosf(ang, &sn, &cs);
  tab[idx] = make_float2(cs, sn);
}

// ---------------------------------------------------------------------------
// GEMM (R11, best measured): 256x256 tile, 8 waves, BK=64 as 2 K-halves,
// 2 phases/K-tile, 32 MFMA/phase, one barrier + one combined vmcnt+lgkm wait
// per phase.
// RAW: (t)k0 retired by PB(t-1)'s vmcnt(8)+barrier; (t)k1 by PA(t)'s
// vmcnt(8)+barrier. WAR: lgkm0 BEFORE each barrier pins every wave's reads;
// the slot staged in the next phase cannot race them.
// Swizzle: global chunk cg at LDS chunk cg^((row>>1)&3); reads use
// csw = (quad ^ ((r16>>1)&3)) -> measured 0 bank conflicts.
// ---------------------------------------------------------------------------
template <typename OutT>
__global__ __launch_bounds__(512, 2) void gemm256_kernel(
    const half_t* __restrict__ A, const half_t* __restrict__ Bt,
    const float* __restrict__ B0, const float* __restrict__ B1,
    const float* __restrict__ B2, OutT* __restrict__ C,
    int M, int N, int K) {
  __shared__ __align__(16) half_t As[2][2][256 * 32];   // [buf][kh] 16KB each
  __shared__ __align__(16) half_t Bs[2][2][256 * 32];

  const int tid = threadIdx.x;
  const int wave = tid >> 6, lane = tid & 63;
  const int r16 = lane & 15, quad = lane >> 4;
  const int wm = wave >> 2, wn = wave & 3;   // 2M x 4N wave grid

  // T1: XCD-chunked swizzle of linear block id (nwg % 8 == 0 for our grids)
  const int nbx = N >> 8;
  const int lid = (int)(blockIdx.y * gridDim.x + blockIdx.x);
  const int nwg = (int)(gridDim.x * gridDim.y);
  const int cpx = nwg >> 3;
  const int swz = (lid & 7) * cpx + (lid >> 3);
  const int brow = (swz / nbx) * 256;
  const int bcol = (swz % nbx) * 256;

  const int NT = K >> 6;   // K/64 tiles

  auto stA = [&](int t, int kh) {
    const int buf = t & 1;
    const int k0 = (t << 6) + (kh << 5);
#pragma unroll
    for (int j = 0; j < 2; ++j) {
      const int s = j * 512 + wave * 64 + lane;
      const int row = s >> 2;
      const int cg = (s & 3) ^ ((row >> 1) & 3);
      gll16(A + (size_t)(brow + row) * K + k0 + cg * 8,
            &As[buf][kh][(j * 512 + wave * 64) * 8]);
    }
  };
  auto stB = [&](int t, int kh) {
    const int buf = t & 1;
    const int k0 = (t << 6) + (kh << 5);
#pragma unroll
    for (int j = 0; j < 2; ++j) {
      const int s = j * 512 + wave * 64 + lane;
      const int row = s >> 2;
      const int cg = (s & 3) ^ ((row >> 1) & 3);
      gll16(Bt + (size_t)(bcol + row) * K + k0 + cg * 8,
            &Bs[buf][kh][(j * 512 + wave * 64) * 8]);
    }
  };

  f32x4 acc[8][4] = {};
  const int csw = (quad ^ ((r16 >> 1) & 3)) << 3;   // swizzled chunk (halfs)

  stA(0, 0); stB(0, 0); stA(0, 1); stB(0, 1); stA(1, 0); stB(1, 0);
  asm volatile("s_waitcnt vmcnt(8)" ::: "memory");
  __builtin_amdgcn_s_barrier();

  for (int t = 0; t < NT; ++t) {
    const int buf = t & 1;
    const half_t* Ak0 = &As[buf][0][0];
    const half_t* Ak1 = &As[buf][1][0];
    const half_t* Bk0 = &Bs[buf][0][0];
    const half_t* Bk1 = &Bs[buf][1][0];
    f16x8 af[4], bf[4], ah[4];

    // ============ PA: kc0, 32 MFMA ============
#pragma unroll
    for (int mi = 0; mi < 4; ++mi)
      af[mi] = *reinterpret_cast<const f16x8*>(
          &Ak0[(wm * 128 + mi * 16 + r16) * 32 + csw]);
#pragma unroll
    for (int ni = 0; ni < 4; ++ni)
      bf[ni] = *reinterpret_cast<const f16x8*>(
          &Bk0[(wn * 64 + ni * 16 + r16) * 32 + csw]);
#pragma unroll
    for (int mi = 0; mi < 4; ++mi)
      ah[mi] = *reinterpret_cast<const f16x8*>(
          &Ak0[(wm * 128 + 64 + mi * 16 + r16) * 32 + csw]);
    if (t + 1 < NT) {
      stA(t + 1, 1); stB(t + 1, 1);
      asm volatile("s_waitcnt vmcnt(8) lgkmcnt(0)" ::: "memory");
    } else {
      asm volatile("s_waitcnt vmcnt(4) lgkmcnt(0)" ::: "memory");
    }
    __builtin_amdgcn_sched_barrier(0);
    __builtin_amdgcn_s_barrier();
    __builtin_amdgcn_sched_barrier(0);
    __builtin_amdgcn_s_setprio(1);
#pragma unroll
    for (int mi = 0; mi < 4; ++mi)
#pragma unroll
      for (int ni = 0; ni < 4; ++ni)
        acc[mi][ni] = __builtin_amdgcn_mfma_f32_16x16x32_f16(
            af[mi], bf[ni], acc[mi][ni], 0, 0, 0);
#pragma unroll
    for (int mi = 0; mi < 4; ++mi)
#pragma unroll
      for (int ni = 0; ni < 4; ++ni)
        acc[mi + 4][ni] = __builtin_amdgcn_mfma_f32_16x16x32_f16(
            ah[mi], bf[ni], acc[mi + 4][ni], 0, 0, 0);
    __builtin_amdgcn_s_setprio(0);

    // ============ PB: kc1, 32 MFMA ============
#pragma unroll
    for (int mi = 0; mi < 4; ++mi)
      af[mi] = *reinterpret_cast<const f16x8*>(
          &Ak1[(wm * 128 + mi * 16 + r16) * 32 + csw]);
#pragma unroll
    for (int ni = 0; ni < 4; ++ni)
      bf[ni] = *reinterpret_cast<const f16x8*>(
          &Bk1[(wn * 64 + ni * 16 + r16) * 32 + csw]);
#pragma unroll
    for (int mi = 0; mi < 4; ++mi)
      ah[mi] = *reinterpret_cast<const f16x8*>(
          &Ak1[(wm * 128 + 64 + mi * 16 + r16) * 32 + csw]);
    if (t + 2 < NT) {
      stA(t + 2, 0); stB(t + 2, 0);
      asm volatile("s_waitcnt vmcnt(8) lgkmcnt(0)" ::: "memory");
    } else if (t + 1 < NT) {
      asm volatile("s_waitcnt vmcnt(8) lgkmcnt(0)" ::: "memory");
    } else {
      asm volatile("s_waitcnt vmcnt(0) lgkmcnt(0)" ::: "memory");
    }
    __builtin_amdgcn_sched_barrier(0);
    __builtin_amdgcn_s_barrier();
    __builtin_amdgcn_sched_barrier(0);
    __builtin_amdgcn_s_setprio(1);
#pragma unroll
    for (int mi = 0; mi < 4; ++mi)
#pragma unroll
      for (int ni = 0; ni < 4; ++ni)
        acc[mi][ni] = __builtin_amdgcn_mfma_f32_16x16x32_f16(
            af[mi], bf[ni], acc[mi][ni], 0, 0, 0);
#pragma unroll
    for (int mi = 0; mi < 4; ++mi)
#pragma unroll
      for (int ni = 0; ni < 4; ++ni)
        acc[mi + 4][ni] = __builtin_amdgcn_mfma_f32_16x16x32_f16(
            ah[mi], bf[ni], acc[mi + 4][ni], 0, 0, 0);
    __builtin_amdgcn_s_setprio(0);
  }

  // epilogue: D row = (lane>>4)*4 + reg, col = lane&15 (verified C/D layout)
#pragma unroll
  for (int ni = 0; ni < 4; ++ni) {
    const int col = bcol + wn * 64 + ni * 16 + r16;
    float bv = 0.0f;
    if (B0) bv = (col < ND) ? B0[col]
                            : (col < ND + NKV * NHD ? B1[col - ND]
                                                    : B2[col - ND - NKV * NHD]);
#pragma unroll
    for (int mi = 0; mi < 8; ++mi) {
      const int row0 = brow + wm * 128 + mi * 16 + quad * 4;
#pragma unroll
      for (int i = 0; i < 4; ++i)
        C[(size_t)(row0 + i) * N + col] = (OutT)(acc[mi][ni][i] + bv);
    }
  }
}

// ---------------------------------------------------------------------------
// RoPE (half-split, table-driven) + reshape for Q and K from merged raw fp16.
// R15: 4 d-values per thread — 8B vector loads/stores (G13), 4x fewer threads.
// hp<32: Q head hp (QK_SCALE folded); else K head hp-32.
// ---------------------------------------------------------------------------
__global__ void ropepack_kernel(const half_t* __restrict__ rawh,
                                const float2* __restrict__ tab,
                                half_t* __restrict__ qb,
                                half_t* __restrict__ kb) {
  const size_t idx = (size_t)blockIdx.x * 256 + threadIdx.x;
  const int d0 = (int)(idx & 15) * 4;          // d0, d0+1, d0+2, d0+3
  size_t t = idx >> 4;
  const int hp = (int)(t % (NH + NKV)); t /= (NH + NKV);
  const int l = (int)(t % NL);
  const int b = (int)(t / NL);
  const bool isQ = hp < NH;
  const int col0 = isQ ? hp * NHD : ND + (hp - NH) * NHD;
  const half_t* src = rawh + ((size_t)b * NL + l) * NQKV + col0;
  const f16x4 x1v = *reinterpret_cast<const f16x4*>(&src[d0]);
  const f16x4 x2v = *reinterpret_cast<const f16x4*>(&src[d0 + 64]);
  const float scale = isQ ? QK_SCALE : 1.0f;
  half_t* dst = isQ ? qb + ((size_t)(b * NH + hp) * NL + l) * NHD
                    : kb + ((size_t)(b * NKV + (hp - NH)) * NL + l) * NHD;
  f16x4 o1, o2;
#pragma unroll
  for (int j = 0; j < 4; ++j) {
    const float2 cssn = tab[(size_t)l * 64 + d0 + j];
    const float x1 = (float)x1v[j];
    const float x2 = (float)x2v[j];
    o1[j] = (half_t)((x1 * cssn.x - x2 * cssn.y) * scale);
    o2[j] = (half_t)((x2 * cssn.x + x1 * cssn.y) * scale);
  }
  *reinterpret_cast<f16x4*>(&dst[d0])      = o1;
  *reinterpret_cast<f16x4*>(&dst[d0 + 64]) = o2;
}

// ---------------------------------------------------------------------------
// V: merged raw fp16 cols [5120,6144) -> Vt [B, KV, HD, L] fp16 (transpose)
// ---------------------------------------------------------------------------
__global__ void vtrans16_kernel(const half_t* __restrict__ rawh,
                                half_t* __restrict__ Vt) {
  __shared__ half_t tile[32][34];
  const int bkv = blockIdx.z;
  const int l0 = blockIdx.x * 32;
  const int d0 = blockIdx.y * 32;
  const int b = bkv / NKV, kvh = bkv % NKV;
  const int tx = threadIdx.x, ty = threadIdx.y;   // block (32,8)
#pragma unroll
  for (int r = 0; r < 32; r += 8)
    tile[ty + r][tx] = rawh[(size_t)(b * NL + l0 + ty + r) * NQKV
                            + ND + NKV * NHD + kvh * NHD + d0 + tx];
  __syncthreads();
  half_t* dst = Vt + (size_t)bkv * NHD * NL;
#pragma unroll
  for (int r = 0; r < 32; r += 8)
    dst[(size_t)(d0 + ty + r) * NL + l0 + tx] = tile[tx][ty + r];
}

// ---------------------------------------------------------------------------
// Flash attention (non-causal, GQA). 8 waves x 32 Q-rows = 256 rows/block.
// R11 version (best measured): KVB=64, K/V double-buffered in LDS (80KB),
// XOR chunk-swizzled, fixed-ref M0 softmax with per-lane deferred row-sum +
// rare wave-uniform fallback rescale, T5 setprio on MFMA clusters.
// ---------------------------------------------------------------------------
#define KVB 64

__global__ __launch_bounds__(512, 2) void attn_kernel(
    const half_t* __restrict__ Q,   // [B,H,L,HD] scaled
    const half_t* __restrict__ Kh,  // [B,KV,L,HD]
    const half_t* __restrict__ Vt,  // [B,KV,HD,L]
    half_t* __restrict__ O) {
  __shared__ half_t Ks[2][KVB * NHD];   // 2 x 16KB
  __shared__ half_t Vs[2][NHD * KVB];   // 2 x 16KB
  __shared__ half_t Ps[8][16 * 64];     // 16KB, per-wave P tile

  const int tid = threadIdx.x;
  const int wave = tid >> 6, lane = tid & 63;
  const int r16 = lane & 15, quad = lane >> 4;
  const int r7 = r16 & 7;

  // XCD-chunked swizzle: 64 consecutive work-items per XCD (512 = 8*64)
  const int bid = (int)blockIdx.x;
  const int swz = (bid & 7) * 64 + (bid >> 3);
  const int nqt = NL / 256;                    // 8
  const int bh = swz / nqt, qt = swz % nqt;
  const int b = bh / NH, h = bh % NH;
  const int kvh = h / NG;

  const int qrow0 = qt * 256 + wave * 32;
  const half_t* Qb = Q  + ((size_t)(b * NH + h) * NL + qrow0) * NHD;
  const half_t* Kb = Kh + ((size_t)(b * NKV + kvh) * NL) * NHD;
  const half_t* Vb = Vt + ((size_t)(b * NKV + kvh) * NHD) * NL;
  half_t* Pw = &Ps[wave][0];

  // ---- stage(buf, n0): K tile 1024 slots, V tile 1024 slots (16B each) ----
  auto stage = [&](int buf, int n0) {
#pragma unroll
    for (int j = 0; j < 2; ++j) {
      const int slot = j * 512 + wave * 64 + lane;
      {
        const int row = slot >> 4;                    // key row 0..63
        const int c = (slot & 15) ^ (row & 7);        // global chunk
        gll16(Kb + (size_t)(n0 + row) * NHD + c * 8,
              &Ks[buf][(j * 512 + wave * 64) * 8]);
      }
      {
        const int row = slot >> 3;                    // d row 0..127
        const int c = (slot & 7) ^ (row & 7);
        gll16(Vb + (size_t)row * NL + n0 + c * 8,
              &Vs[buf][(j * 512 + wave * 64) * 8]);
      }
    }
  };

  stage(0, 0);

  // Q fragments: 2 row-tiles x 4 k-chunks
  f16x8 qf[2][4];
#pragma unroll
  for (int rt = 0; rt < 2; ++rt)
#pragma unroll
    for (int c = 0; c < 4; ++c)
      qf[rt][c] = *reinterpret_cast<const f16x8*>(
          &Qb[(size_t)(rt * 16 + r16) * NHD + c * 32 + quad * 8]);

  f32x4 oacc[2][8];
  float m_run[2][4], lsum[2][4];
#pragma unroll
  for (int rt = 0; rt < 2; ++rt) {
#pragma unroll
    for (int i = 0; i < 4; ++i) { m_run[rt][i] = M0; lsum[rt][i] = 0.0f; }
#pragma unroll
    for (int dt = 0; dt < 8; ++dt) oacc[rt][dt] = (f32x4){0.f, 0.f, 0.f, 0.f};
  }

  // P read swizzle (row = r16): mask = (r16&7) ^ ((r16>>3)*5)
  const int swzread = r7 ^ ((r16 >> 3) * 5);

  asm volatile("s_waitcnt vmcnt(0)" ::: "memory");
  __syncthreads();

  int cur = 0;
  for (int t = 0; t < NL / KVB; ++t, cur ^= 1) {
    if (t + 1 < NL / KVB) stage(cur ^ 1, (t + 1) * KVB);

    const half_t* Kc = &Ks[cur][0];
    const half_t* Vc = &Vs[cur][0];

    // ---- S = Q K^T (swizzled K reads) ----
    f32x4 s[2][4] = {};
    __builtin_amdgcn_s_setprio(1);
#pragma unroll
    for (int c = 0; c < 4; ++c) {
      const int ch = ((c * 4 + quad) ^ r7) * 8;
#pragma unroll
      for (int nt = 0; nt < 4; ++nt) {
        f16x8 kf = *reinterpret_cast<const f16x8*>(&Kc[(nt * 16 + r16) * NHD + ch]);
        s[0][nt] = __builtin_amdgcn_mfma_f32_16x16x32_f16(qf[0][c], kf, s[0][nt], 0, 0, 0);
        s[1][nt] = __builtin_amdgcn_mfma_f32_16x16x32_f16(qf[1][c], kf, s[1][nt], 0, 0, 0);
      }
    }
    __builtin_amdgcn_s_setprio(0);

    // ---- fallback check: any lane-local score above running ref? ----
    float mx[2][4];
    bool need = false;
#pragma unroll
    for (int rt = 0; rt < 2; ++rt)
#pragma unroll
      for (int i = 0; i < 4; ++i) {
        mx[rt][i] = fmaxf(fmaxf(s[rt][0][i], s[rt][1][i]),
                          fmaxf(s[rt][2][i], s[rt][3][i]));
        need = need || (mx[rt][i] > m_run[rt][i] + THR);
      }
    if (__any(need ? 1 : 0)) {   // rare: full reduce + rescale (correctness)
#pragma unroll
      for (int rt = 0; rt < 2; ++rt)
#pragma unroll
        for (int i = 0; i < 4; ++i) {
          float m = mx[rt][i];
#pragma unroll
          for (int off = 1; off < 16; off <<= 1)
            m = fmaxf(m, __shfl_xor(m, off));
          const float mn = fmaxf(m_run[rt][i], m);
          const float corr = exp2f((m_run[rt][i] - mn) * RLOG2E);
          m_run[rt][i] = mn;
          lsum[rt][i] *= corr;
#pragma unroll
          for (int dt = 0; dt < 8; ++dt) oacc[rt][dt][i] *= corr;
        }
    }

    // ---- P = exp(S - m), per-lane partial sums, swizzled LDS writes ----
    f16x8 pa[2][2];
#pragma unroll
    for (int rt = 0; rt < 2; ++rt) {
#pragma unroll
      for (int i = 0; i < 4; ++i) {
        const float mrl = m_run[rt][i] * RLOG2E;
        float p[4];
#pragma unroll
        for (int nt = 0; nt < 4; ++nt)
          p[nt] = exp2f(s[rt][nt][i] * RLOG2E - mrl);
        lsum[rt][i] += (p[0] + p[1]) + (p[2] + p[3]);
        const int row = quad * 4 + i;
        const int swzr = (row & 7) ^ ((row >> 3) * 5);
#pragma unroll
        for (int nt = 0; nt < 4; ++nt)
          Pw[row * 64 + (((nt * 2 + (r16 >> 3)) ^ swzr) * 8) + r7] = (half_t)p[nt];
      }
      // A-fragments (wave-private LDS; in-order DS pipe, no barrier)
      pa[rt][0] = *reinterpret_cast<const f16x8*>(&Pw[r16 * 64 + ((quad ^ swzread) * 8)]);
      pa[rt][1] = *reinterpret_cast<const f16x8*>(&Pw[r16 * 64 + (((4 + quad) ^ swzread) * 8)]);
    }

    // ---- O += P V (swizzled V reads, shared across both row-tiles) ----
    const int ch0 = (quad ^ r7) * 8;
    const int ch1 = ((4 + quad) ^ r7) * 8;
    __builtin_amdgcn_s_setprio(1);
#pragma unroll
    for (int dt = 0; dt < 8; ++dt) {
      const int row = dt * 16 + r16;
      f16x8 v0 = *reinterpret_cast<const f16x8*>(&Vc[row * 64 + ch0]);
      f16x8 v1 = *reinterpret_cast<const f16x8*>(&Vc[row * 64 + ch1]);
      oacc[0][dt] = __builtin_amdgcn_mfma_f32_16x16x32_f16(pa[0][0], v0, oacc[0][dt], 0, 0, 0);
      oacc[0][dt] = __builtin_amdgcn_mfma_f32_16x16x32_f16(pa[0][1], v1, oacc[0][dt], 0, 0, 0);
      oacc[1][dt] = __builtin_amdgcn_mfma_f32_16x16x32_f16(pa[1][0], v0, oacc[1][dt], 0, 0, 0);
      oacc[1][dt] = __builtin_amdgcn_mfma_f32_16x16x32_f16(pa[1][1], v1, oacc[1][dt], 0, 0, 0);
    }
    __builtin_amdgcn_s_setprio(0);

    asm volatile("s_waitcnt vmcnt(0)" ::: "memory");
    __syncthreads();
  }

  // ---- epilogue: one deferred row-sum reduce, normalize, write fp16 ----
  half_t* Ob = O + ((size_t)(b * NL) + qrow0) * (NH * NHD) + (size_t)h * NHD;
#pragma unroll
  for (int rt = 0; rt < 2; ++rt)
#pragma unroll
    for (int i = 0; i < 4; ++i) {
      float l = lsum[rt][i];
#pragma unroll
      for (int off = 1; off < 16; off <<= 1)
        l += __shfl_xor(l, off);
      const float inv = 1.0f / l;
      const int rl = rt * 16 + quad * 4 + i;
#pragma unroll
      for (int dt = 0; dt < 8; ++dt)
        Ob[(size_t)rl * (NH * NHD) + dt * 16 + r16] =
            (half_t)(oacc[rt][dt][i] * inv);
    }
}

// ---------------------------------------------------------------------------
extern "C" void kernel_launch(void* const* d_in, const int* in_sizes, int n_in,
                              void* d_out, int out_size, void* d_ws, size_t ws_size,
                              hipStream_t stream) {
  const float* x  = (const float*)d_in[0];
  const float* Wq = (const float*)d_in[1];
  const float* bq = (const float*)d_in[2];
  const float* Wk = (const float*)d_in[3];
  const float* bk = (const float*)d_in[4];
  const float* Wv = (const float*)d_in[5];
  const float* bv = (const float*)d_in[6];
  const float* Wo = (const float*)d_in[7];
  float* out = (float*)d_out;

  char* ws = (char*)d_ws;
  size_t off = 0;
  auto alloc = [&](size_t bytes) {
    size_t cur = off;
    off += (bytes + 255) & ~(size_t)255;
    return cur;
  };
  const size_t M = (size_t)NB * NL;  // 4096 token rows
  // buffer plan (~186 MB):
  half_t* xb   = (half_t*)(ws + alloc(M * ND * 2));            // x fp16; reused as AttnOut
  half_t* wqkv = (half_t*)(ws + alloc((size_t)NQKV * ND * 2)); // [Wq;Wk;Wv]^T; reused for Wo^T
  half_t* rawh = (half_t*)(ws + alloc(M * NQKV * 2));          // merged QKV raw fp16
  half_t* qb   = (half_t*)(ws + alloc(M * (size_t)(NH * NHD) * 2));
  half_t* kb   = (half_t*)(ws + alloc(M * (size_t)(NKV * NHD) * 2));
  half_t* vt   = (half_t*)(ws + alloc(M * (size_t)(NKV * NHD) * 2));
  float2* tab  = (float2*)(ws + alloc((size_t)NL * 64 * 8));   // RoPE cos/sin

  // 1) x -> fp16 ; RoPE table
  {
    int n4 = (int)(M * ND / 4);
    convert_f32_f16_kernel<<<dim3((n4 + 255) / 256), dim3(256), 0, stream>>>(x, xb, n4);
  }
  ropetab_kernel<<<dim3(NL * 64 / 256), dim3(256), 0, stream>>>(tab);

  // 2) weight transposes into merged [6144][4096] fp16
  wtrans_kernel<<<dim3(ND / 32, ND / 32), dim3(32, 8), 0, stream>>>(
      Wq, wqkv, ND, ND);
  wtrans_kernel<<<dim3((NKV * NHD) / 32, ND / 32), dim3(32, 8), 0, stream>>>(
      Wk, wqkv + (size_t)ND * ND, ND, NKV * NHD);
  wtrans_kernel<<<dim3((NKV * NHD) / 32, ND / 32), dim3(32, 8), 0, stream>>>(
      Wv, wqkv + (size_t)(ND + NKV * NHD) * ND, ND, NKV * NHD);

  // 3) merged QKV GEMM -> rawh fp16 (bias fused, 3-way select)
  gemm256_kernel<half_t><<<dim3(NQKV / 256, M / 256), dim3(512), 0, stream>>>(
      xb, wqkv, bq, bk, bv, rawh, (int)M, NQKV, ND);

  // 4) RoPE+pack Q,K (table-driven, 4 d/thread); transpose V
  ropepack_kernel<<<dim3((unsigned)(M * (NH + NKV) * 16 / 256)), dim3(256), 0, stream>>>(
      rawh, tab, qb, kb);
  vtrans16_kernel<<<dim3(NL / 32, NHD / 32, NB * NKV), dim3(32, 8), 0, stream>>>(rawh, vt);

  // 5) Wo^T into wqkv (dead after step 3; stream order guarantees safety)
  wtrans_kernel<<<dim3(ND / 32, ND / 32), dim3(32, 8), 0, stream>>>(Wo, wqkv, NH * NHD, ND);

  // 6) attention -> xb (reused as AttnOut, [B*L, H*HD] fp16)
  attn_kernel<<<dim3(NB * NH * (NL / 256)), dim3(512), 0, stream>>>(qb, kb, vt, xb);

  // 7) output projection -> d_out (fp32)
  gemm256_kernel<float><<<dim3(ND / 256, M / 256), dim3(512), 0, stream>>>(
      xb, wqkv, nullptr, nullptr, nullptr, out, (int)M, ND, ND);
}

// Round 16
// 638.654 us; speedup vs baseline: 1.4008x; 1.0013x over previous
//
#include <hip/hip_runtime.h>
#include <stdint.h>
#include <stddef.h>

// ---------------------------------------------------------------------------
// Fused GQA attention block: QKV proj + half-split RoPE + flash attention +
// output proj. fp16 MFMA (16x16x32) everywhere, fp32 accumulate/softmax.
// R16: R15 (verified best, 639us) + G13 vectorization of the two transpose
// kernels (wtrans: float4 in / f16x4 out; vtrans: f16x4 in/out). All MFMA
// kernels byte-identical to R15.
// Schedule-space record: GEMM 2-phase/lgkm0-before-barrier (R11) is the
// measured optimum (40% MfmaUtil; 1-barrier=25%, 8-barrier=34.5%,
// reg-pipeline=29% — fragment pipelining breaks the 2-waves/SIMD register
// budget). Attn 2-blocks/CU infeasible (oacc AGPR + VGPR ~172/wave).
// ---------------------------------------------------------------------------

typedef _Float16 half_t;
typedef __attribute__((ext_vector_type(4))) _Float16 f16x4;
typedef __attribute__((ext_vector_type(8))) _Float16 f16x8;
typedef __attribute__((ext_vector_type(4))) float f32x4;

#define NB 2
#define NL 2048
#define ND 4096
#define NH 32
#define NKV 8
#define NHD 128
#define NG 4               // H / KV
#define NQKV 6144          // H*HD + 2*KV*HD
#define QK_SCALE 0.08838834764831845f   // HD^-0.5
#define RLOG2E 1.4426950408889634f
#define M0 6.0f            // fixed softmax reference (scores ~N(0,1.64^2))
#define THR 8.0f           // defer-max threshold (fallback if mx > M0+THR)

// async global->LDS, 16B per lane. LDS dest must be wave-uniform base;
// lane i lands at base + i*16 (HW-defined linear scatter).
static __device__ __forceinline__ void gll16(const void* g, void* l) {
  __builtin_amdgcn_global_load_lds(
      (__attribute__((address_space(1))) void*)(void*)(g),
      (__attribute__((address_space(3))) void*)(l),
      16, 0, 0);
}

// ---------------------------------------------------------------------------
// elementwise fp32 -> fp16 (vectorized: float4 in, 4xfp16 out)
// ---------------------------------------------------------------------------
__global__ void convert_f32_f16_kernel(const float* __restrict__ in,
                                       half_t* __restrict__ out, int n4) {
  int i = blockIdx.x * 256 + threadIdx.x;
  if (i >= n4) return;
  const float4 v = reinterpret_cast<const float4*>(in)[i];
  f16x4 o;
  o[0] = (half_t)v.x; o[1] = (half_t)v.y; o[2] = (half_t)v.z; o[3] = (half_t)v.w;
  reinterpret_cast<f16x4*>(out)[i] = o;
}

// ---------------------------------------------------------------------------
// W [K,N] fp32 row-major -> Wt [N,K] fp16 row-major. R16: block (8,32),
// float4 loads (16B/lane), f16x4 stores (8B/lane).
// load: tile[l=ty][c=tx*4+j] = W[k0+ty][n0+tx*4+j]
// store: Wt[n0+ty][k0+tx*4+j] = tile[tx*4+j][ty]  (transpose verified)
// Store-read bank: ((tx*4+j)*33+ty)%32 = (tx*4+j+ty)%32 -> <=2-way (free).
// ---------------------------------------------------------------------------
__global__ void wtrans_kernel(const float* __restrict__ W,
                              half_t* __restrict__ Wt, int K, int N) {
  __shared__ float tile[32][33];
  const int n0 = blockIdx.x * 32;
  const int k0 = blockIdx.y * 32;
  const int tx = threadIdx.x, ty = threadIdx.y;   // block (8,32)
  const float4 v = *reinterpret_cast<const float4*>(
      &W[(size_t)(k0 + ty) * N + n0 + tx * 4]);
  tile[ty][tx * 4 + 0] = v.x;
  tile[ty][tx * 4 + 1] = v.y;
  tile[ty][tx * 4 + 2] = v.z;
  tile[ty][tx * 4 + 3] = v.w;
  __syncthreads();
  f16x4 o;
#pragma unroll
  for (int j = 0; j < 4; ++j)
    o[j] = (half_t)tile[tx * 4 + j][ty];
  *reinterpret_cast<f16x4*>(&Wt[(size_t)(n0 + ty) * K + k0 + tx * 4]) = o;
}

// ---------------------------------------------------------------------------
// RoPE sin/cos table: tab[l*64+d] = {cos(l*invfreq(d)), sin(l*invfreq(d))}
// ---------------------------------------------------------------------------
__global__ void ropetab_kernel(float2* __restrict__ tab) {
  const int idx = blockIdx.x * 256 + threadIdx.x;   // NL*64 entries
  const int d = idx & 63;
  const int l = idx >> 6;
  const float inv_freq = exp2f(-(float)d * 0.20762050593045935f);
  const float ang = (float)l * inv_freq;
  float sn, cs;
  __sincosf(ang, &sn, &cs);
  tab[idx] = make_float2(cs, sn);
}

// ---------------------------------------------------------------------------
// GEMM (R11, best measured): 256x256 tile, 8 waves, BK=64 as 2 K-halves,
// 2 phases/K-tile, 32 MFMA/phase, one barrier + one combined vmcnt+lgkm wait
// per phase.
// RAW: (t)k0 retired by PB(t-1)'s vmcnt(8)+barrier; (t)k1 by PA(t)'s
// vmcnt(8)+barrier. WAR: lgkm0 BEFORE each barrier pins every wave's reads;
// the slot staged in the next phase cannot race them.
// Swizzle: global chunk cg at LDS chunk cg^((row>>1)&3); reads use
// csw = (quad ^ ((r16>>1)&3)) -> measured 0 bank conflicts.
// ---------------------------------------------------------------------------
template <typename OutT>
__global__ __launch_bounds__(512, 2) void gemm256_kernel(
    const half_t* __restrict__ A, const half_t* __restrict__ Bt,
    const float* __restrict__ B0, const float* __restrict__ B1,
    const float* __restrict__ B2, OutT* __restrict__ C,
    int M, int N, int K) {
  __shared__ __align__(16) half_t As[2][2][256 * 32];   // [buf][kh] 16KB each
  __shared__ __align__(16) half_t Bs[2][2][256 * 32];

  const int tid = threadIdx.x;
  const int wave = tid >> 6, lane = tid & 63;
  const int r16 = lane & 15, quad = lane >> 4;
  const int wm = wave >> 2, wn = wave & 3;   // 2M x 4N wave grid

  // T1: XCD-chunked swizzle of linear block id (nwg % 8 == 0 for our grids)
  const int nbx = N >> 8;
  const int lid = (int)(blockIdx.y * gridDim.x + blockIdx.x);
  const int nwg = (int)(gridDim.x * gridDim.y);
  const int cpx = nwg >> 3;
  const int swz = (lid & 7) * cpx + (lid >> 3);
  const int brow = (swz / nbx) * 256;
  const int bcol = (swz % nbx) * 256;

  const int NT = K >> 6;   // K/64 tiles

  auto stA = [&](int t, int kh) {
    const int buf = t & 1;
    const int k0 = (t << 6) + (kh << 5);
#pragma unroll
    for (int j = 0; j < 2; ++j) {
      const int s = j * 512 + wave * 64 + lane;
      const int row = s >> 2;
      const int cg = (s & 3) ^ ((row >> 1) & 3);
      gll16(A + (size_t)(brow + row) * K + k0 + cg * 8,
            &As[buf][kh][(j * 512 + wave * 64) * 8]);
    }
  };
  auto stB = [&](int t, int kh) {
    const int buf = t & 1;
    const int k0 = (t << 6) + (kh << 5);
#pragma unroll
    for (int j = 0; j < 2; ++j) {
      const int s = j * 512 + wave * 64 + lane;
      const int row = s >> 2;
      const int cg = (s & 3) ^ ((row >> 1) & 3);
      gll16(Bt + (size_t)(bcol + row) * K + k0 + cg * 8,
            &Bs[buf][kh][(j * 512 + wave * 64) * 8]);
    }
  };

  f32x4 acc[8][4] = {};
  const int csw = (quad ^ ((r16 >> 1) & 3)) << 3;   // swizzled chunk (halfs)

  stA(0, 0); stB(0, 0); stA(0, 1); stB(0, 1); stA(1, 0); stB(1, 0);
  asm volatile("s_waitcnt vmcnt(8)" ::: "memory");
  __builtin_amdgcn_s_barrier();

  for (int t = 0; t < NT; ++t) {
    const int buf = t & 1;
    const half_t* Ak0 = &As[buf][0][0];
    const half_t* Ak1 = &As[buf][1][0];
    const half_t* Bk0 = &Bs[buf][0][0];
    const half_t* Bk1 = &Bs[buf][1][0];
    f16x8 af[4], bf[4], ah[4];

    // ============ PA: kc0, 32 MFMA ============
#pragma unroll
    for (int mi = 0; mi < 4; ++mi)
      af[mi] = *reinterpret_cast<const f16x8*>(
          &Ak0[(wm * 128 + mi * 16 + r16) * 32 + csw]);
#pragma unroll
    for (int ni = 0; ni < 4; ++ni)
      bf[ni] = *reinterpret_cast<const f16x8*>(
          &Bk0[(wn * 64 + ni * 16 + r16) * 32 + csw]);
#pragma unroll
    for (int mi = 0; mi < 4; ++mi)
      ah[mi] = *reinterpret_cast<const f16x8*>(
          &Ak0[(wm * 128 + 64 + mi * 16 + r16) * 32 + csw]);
    if (t + 1 < NT) {
      stA(t + 1, 1); stB(t + 1, 1);
      asm volatile("s_waitcnt vmcnt(8) lgkmcnt(0)" ::: "memory");
    } else {
      asm volatile("s_waitcnt vmcnt(4) lgkmcnt(0)" ::: "memory");
    }
    __builtin_amdgcn_sched_barrier(0);
    __builtin_amdgcn_s_barrier();
    __builtin_amdgcn_sched_barrier(0);
    __builtin_amdgcn_s_setprio(1);
#pragma unroll
    for (int mi = 0; mi < 4; ++mi)
#pragma unroll
      for (int ni = 0; ni < 4; ++ni)
        acc[mi][ni] = __builtin_amdgcn_mfma_f32_16x16x32_f16(
            af[mi], bf[ni], acc[mi][ni], 0, 0, 0);
#pragma unroll
    for (int mi = 0; mi < 4; ++mi)
#pragma unroll
      for (int ni = 0; ni < 4; ++ni)
        acc[mi + 4][ni] = __builtin_amdgcn_mfma_f32_16x16x32_f16(
            ah[mi], bf[ni], acc[mi + 4][ni], 0, 0, 0);
    __builtin_amdgcn_s_setprio(0);

    // ============ PB: kc1, 32 MFMA ============
#pragma unroll
    for (int mi = 0; mi < 4; ++mi)
      af[mi] = *reinterpret_cast<const f16x8*>(
          &Ak1[(wm * 128 + mi * 16 + r16) * 32 + csw]);
#pragma unroll
    for (int ni = 0; ni < 4; ++ni)
      bf[ni] = *reinterpret_cast<const f16x8*>(
          &Bk1[(wn * 64 + ni * 16 + r16) * 32 + csw]);
#pragma unroll
    for (int mi = 0; mi < 4; ++mi)
      ah[mi] = *reinterpret_cast<const f16x8*>(
          &Ak1[(wm * 128 + 64 + mi * 16 + r16) * 32 + csw]);
    if (t + 2 < NT) {
      stA(t + 2, 0); stB(t + 2, 0);
      asm volatile("s_waitcnt vmcnt(8) lgkmcnt(0)" ::: "memory");
    } else if (t + 1 < NT) {
      asm volatile("s_waitcnt vmcnt(8) lgkmcnt(0)" ::: "memory");
    } else {
      asm volatile("s_waitcnt vmcnt(0) lgkmcnt(0)" ::: "memory");
    }
    __builtin_amdgcn_sched_barrier(0);
    __builtin_amdgcn_s_barrier();
    __builtin_amdgcn_sched_barrier(0);
    __builtin_amdgcn_s_setprio(1);
#pragma unroll
    for (int mi = 0; mi < 4; ++mi)
#pragma unroll
      for (int ni = 0; ni < 4; ++ni)
        acc[mi][ni] = __builtin_amdgcn_mfma_f32_16x16x32_f16(
            af[mi], bf[ni], acc[mi][ni], 0, 0, 0);
#pragma unroll
    for (int mi = 0; mi < 4; ++mi)
#pragma unroll
      for (int ni = 0; ni < 4; ++ni)
        acc[mi + 4][ni] = __builtin_amdgcn_mfma_f32_16x16x32_f16(
            ah[mi], bf[ni], acc[mi + 4][ni], 0, 0, 0);
    __builtin_amdgcn_s_setprio(0);
  }

  // epilogue: D row = (lane>>4)*4 + reg, col = lane&15 (verified C/D layout)
#pragma unroll
  for (int ni = 0; ni < 4; ++ni) {
    const int col = bcol + wn * 64 + ni * 16 + r16;
    float bv = 0.0f;
    if (B0) bv = (col < ND) ? B0[col]
                            : (col < ND + NKV * NHD ? B1[col - ND]
                                                    : B2[col - ND - NKV * NHD]);
#pragma unroll
    for (int mi = 0; mi < 8; ++mi) {
      const int row0 = brow + wm * 128 + mi * 16 + quad * 4;
#pragma unroll
      for (int i = 0; i < 4; ++i)
        C[(size_t)(row0 + i) * N + col] = (OutT)(acc[mi][ni][i] + bv);
    }
  }
}

// ---------------------------------------------------------------------------
// RoPE (half-split, table-driven) + reshape for Q and K from merged raw fp16.
// 4 d-values per thread — 8B vector loads/stores (G13), 4x fewer threads.
// hp<32: Q head hp (QK_SCALE folded); else K head hp-32.
// ---------------------------------------------------------------------------
__global__ void ropepack_kernel(const half_t* __restrict__ rawh,
                                const float2* __restrict__ tab,
                                half_t* __restrict__ qb,
                                half_t* __restrict__ kb) {
  const size_t idx = (size_t)blockIdx.x * 256 + threadIdx.x;
  const int d0 = (int)(idx & 15) * 4;          // d0, d0+1, d0+2, d0+3
  size_t t = idx >> 4;
  const int hp = (int)(t % (NH + NKV)); t /= (NH + NKV);
  const int l = (int)(t % NL);
  const int b = (int)(t / NL);
  const bool isQ = hp < NH;
  const int col0 = isQ ? hp * NHD : ND + (hp - NH) * NHD;
  const half_t* src = rawh + ((size_t)b * NL + l) * NQKV + col0;
  const f16x4 x1v = *reinterpret_cast<const f16x4*>(&src[d0]);
  const f16x4 x2v = *reinterpret_cast<const f16x4*>(&src[d0 + 64]);
  const float scale = isQ ? QK_SCALE : 1.0f;
  half_t* dst = isQ ? qb + ((size_t)(b * NH + hp) * NL + l) * NHD
                    : kb + ((size_t)(b * NKV + (hp - NH)) * NL + l) * NHD;
  f16x4 o1, o2;
#pragma unroll
  for (int j = 0; j < 4; ++j) {
    const float2 cssn = tab[(size_t)l * 64 + d0 + j];
    const float x1 = (float)x1v[j];
    const float x2 = (float)x2v[j];
    o1[j] = (half_t)((x1 * cssn.x - x2 * cssn.y) * scale);
    o2[j] = (half_t)((x2 * cssn.x + x1 * cssn.y) * scale);
  }
  *reinterpret_cast<f16x4*>(&dst[d0])      = o1;
  *reinterpret_cast<f16x4*>(&dst[d0 + 64]) = o2;
}

// ---------------------------------------------------------------------------
// V: merged raw fp16 cols [5120,6144) -> Vt [B, KV, HD, L] fp16.
// R16: block (8,32), f16x4 loads/stores (8B/lane).
// load:  tile[l=ty][d=tx*4+j] = rawh[l0+ty][dcol0 + d0+tx*4+j]
// store: Vt[d0+ty][l0+tx*4+j] = tile[tx*4+j][ty]  (transpose verified)
// [34]-pad: store-read bank = (tx*4+ty/2+j*17)%32, (tx,ty/2) bijective
// over 32 banks -> conflict-free.
// ---------------------------------------------------------------------------
__global__ void vtrans16_kernel(const half_t* __restrict__ rawh,
                                half_t* __restrict__ Vt) {
  __shared__ half_t tile[32][34];
  const int bkv = blockIdx.z;
  const int l0 = blockIdx.x * 32;
  const int d0 = blockIdx.y * 32;
  const int b = bkv / NKV, kvh = bkv % NKV;
  const int tx = threadIdx.x, ty = threadIdx.y;   // block (8,32)
  const f16x4 v = *reinterpret_cast<const f16x4*>(
      &rawh[(size_t)(b * NL + l0 + ty) * NQKV
            + ND + NKV * NHD + kvh * NHD + d0 + tx * 4]);
#pragma unroll
  for (int j = 0; j < 4; ++j) tile[ty][tx * 4 + j] = v[j];
  __syncthreads();
  half_t* dst = Vt + (size_t)bkv * NHD * NL;
  f16x4 o;
#pragma unroll
  for (int j = 0; j < 4; ++j) o[j] = tile[tx * 4 + j][ty];
  *reinterpret_cast<f16x4*>(&dst[(size_t)(d0 + ty) * NL + l0 + tx * 4]) = o;
}

// ---------------------------------------------------------------------------
// Flash attention (non-causal, GQA). 8 waves x 32 Q-rows = 256 rows/block.
// R11 version (best measured): KVB=64, K/V double-buffered in LDS (80KB),
// XOR chunk-swizzled, fixed-ref M0 softmax with per-lane deferred row-sum +
// rare wave-uniform fallback rescale, T5 setprio on MFMA clusters.
// ---------------------------------------------------------------------------
#define KVB 64

__global__ __launch_bounds__(512, 2) void attn_kernel(
    const half_t* __restrict__ Q,   // [B,H,L,HD] scaled
    const half_t* __restrict__ Kh,  // [B,KV,L,HD]
    const half_t* __restrict__ Vt,  // [B,KV,HD,L]
    half_t* __restrict__ O) {
  __shared__ half_t Ks[2][KVB * NHD];   // 2 x 16KB
  __shared__ half_t Vs[2][NHD * KVB];   // 2 x 16KB
  __shared__ half_t Ps[8][16 * 64];     // 16KB, per-wave P tile

  const int tid = threadIdx.x;
  const int wave = tid >> 6, lane = tid & 63;
  const int r16 = lane & 15, quad = lane >> 4;
  const int r7 = r16 & 7;

  // XCD-chunked swizzle: 64 consecutive work-items per XCD (512 = 8*64)
  const int bid = (int)blockIdx.x;
  const int swz = (bid & 7) * 64 + (bid >> 3);
  const int nqt = NL / 256;                    // 8
  const int bh = swz / nqt, qt = swz % nqt;
  const int b = bh / NH, h = bh % NH;
  const int kvh = h / NG;

  const int qrow0 = qt * 256 + wave * 32;
  const half_t* Qb = Q  + ((size_t)(b * NH + h) * NL + qrow0) * NHD;
  const half_t* Kb = Kh + ((size_t)(b * NKV + kvh) * NL) * NHD;
  const half_t* Vb = Vt + ((size_t)(b * NKV + kvh) * NHD) * NL;
  half_t* Pw = &Ps[wave][0];

  // ---- stage(buf, n0): K tile 1024 slots, V tile 1024 slots (16B each) ----
  auto stage = [&](int buf, int n0) {
#pragma unroll
    for (int j = 0; j < 2; ++j) {
      const int slot = j * 512 + wave * 64 + lane;
      {
        const int row = slot >> 4;                    // key row 0..63
        const int c = (slot & 15) ^ (row & 7);        // global chunk
        gll16(Kb + (size_t)(n0 + row) * NHD + c * 8,
              &Ks[buf][(j * 512 + wave * 64) * 8]);
      }
      {
        const int row = slot >> 3;                    // d row 0..127
        const int c = (slot & 7) ^ (row & 7);
        gll16(Vb + (size_t)row * NL + n0 + c * 8,
              &Vs[buf][(j * 512 + wave * 64) * 8]);
      }
    }
  };

  stage(0, 0);

  // Q fragments: 2 row-tiles x 4 k-chunks
  f16x8 qf[2][4];
#pragma unroll
  for (int rt = 0; rt < 2; ++rt)
#pragma unroll
    for (int c = 0; c < 4; ++c)
      qf[rt][c] = *reinterpret_cast<const f16x8*>(
          &Qb[(size_t)(rt * 16 + r16) * NHD + c * 32 + quad * 8]);

  f32x4 oacc[2][8];
  float m_run[2][4], lsum[2][4];
#pragma unroll
  for (int rt = 0; rt < 2; ++rt) {
#pragma unroll
    for (int i = 0; i < 4; ++i) { m_run[rt][i] = M0; lsum[rt][i] = 0.0f; }
#pragma unroll
    for (int dt = 0; dt < 8; ++dt) oacc[rt][dt] = (f32x4){0.f, 0.f, 0.f, 0.f};
  }

  // P read swizzle (row = r16): mask = (r16&7) ^ ((r16>>3)*5)
  const int swzread = r7 ^ ((r16 >> 3) * 5);

  asm volatile("s_waitcnt vmcnt(0)" ::: "memory");
  __syncthreads();

  int cur = 0;
  for (int t = 0; t < NL / KVB; ++t, cur ^= 1) {
    if (t + 1 < NL / KVB) stage(cur ^ 1, (t + 1) * KVB);

    const half_t* Kc = &Ks[cur][0];
    const half_t* Vc = &Vs[cur][0];

    // ---- S = Q K^T (swizzled K reads) ----
    f32x4 s[2][4] = {};
    __builtin_amdgcn_s_setprio(1);
#pragma unroll
    for (int c = 0; c < 4; ++c) {
      const int ch = ((c * 4 + quad) ^ r7) * 8;
#pragma unroll
      for (int nt = 0; nt < 4; ++nt) {
        f16x8 kf = *reinterpret_cast<const f16x8*>(&Kc[(nt * 16 + r16) * NHD + ch]);
        s[0][nt] = __builtin_amdgcn_mfma_f32_16x16x32_f16(qf[0][c], kf, s[0][nt], 0, 0, 0);
        s[1][nt] = __builtin_amdgcn_mfma_f32_16x16x32_f16(qf[1][c], kf, s[1][nt], 0, 0, 0);
      }
    }
    __builtin_amdgcn_s_setprio(0);

    // ---- fallback check: any lane-local score above running ref? ----
    float mx[2][4];
    bool need = false;
#pragma unroll
    for (int rt = 0; rt < 2; ++rt)
#pragma unroll
      for (int i = 0; i < 4; ++i) {
        mx[rt][i] = fmaxf(fmaxf(s[rt][0][i], s[rt][1][i]),
                          fmaxf(s[rt][2][i], s[rt][3][i]));
        need = need || (mx[rt][i] > m_run[rt][i] + THR);
      }
    if (__any(need ? 1 : 0)) {   // rare: full reduce + rescale (correctness)
#pragma unroll
      for (int rt = 0; rt < 2; ++rt)
#pragma unroll
        for (int i = 0; i < 4; ++i) {
          float m = mx[rt][i];
#pragma unroll
          for (int off = 1; off < 16; off <<= 1)
            m = fmaxf(m, __shfl_xor(m, off));
          const float mn = fmaxf(m_run[rt][i], m);
          const float corr = exp2f((m_run[rt][i] - mn) * RLOG2E);
          m_run[rt][i] = mn;
          lsum[rt][i] *= corr;
#pragma unroll
          for (int dt = 0; dt < 8; ++dt) oacc[rt][dt][i] *= corr;
        }
    }

    // ---- P = exp(S - m), per-lane partial sums, swizzled LDS writes ----
    f16x8 pa[2][2];
#pragma unroll
    for (int rt = 0; rt < 2; ++rt) {
#pragma unroll
      for (int i = 0; i < 4; ++i) {
        const float mrl = m_run[rt][i] * RLOG2E;
        float p[4];
#pragma unroll
        for (int nt = 0; nt < 4; ++nt)
          p[nt] = exp2f(s[rt][nt][i] * RLOG2E - mrl);
        lsum[rt][i] += (p[0] + p[1]) + (p[2] + p[3]);
        const int row = quad * 4 + i;
        const int swzr = (row & 7) ^ ((row >> 3) * 5);
#pragma unroll
        for (int nt = 0; nt < 4; ++nt)
          Pw[row * 64 + (((nt * 2 + (r16 >> 3)) ^ swzr) * 8) + r7] = (half_t)p[nt];
      }
      // A-fragments (wave-private LDS; in-order DS pipe, no barrier)
      pa[rt][0] = *reinterpret_cast<const f16x8*>(&Pw[r16 * 64 + ((quad ^ swzread) * 8)]);
      pa[rt][1] = *reinterpret_cast<const f16x8*>(&Pw[r16 * 64 + (((4 + quad) ^ swzread) * 8)]);
    }

    // ---- O += P V (swizzled V reads, shared across both row-tiles) ----
    const int ch0 = (quad ^ r7) * 8;
    const int ch1 = ((4 + quad) ^ r7) * 8;
    __builtin_amdgcn_s_setprio(1);
#pragma unroll
    for (int dt = 0; dt < 8; ++dt) {
      const int row = dt * 16 + r16;
      f16x8 v0 = *reinterpret_cast<const f16x8*>(&Vc[row * 64 + ch0]);
      f16x8 v1 = *reinterpret_cast<const f16x8*>(&Vc[row * 64 + ch1]);
      oacc[0][dt] = __builtin_amdgcn_mfma_f32_16x16x32_f16(pa[0][0], v0, oacc[0][dt], 0, 0, 0);
      oacc[0][dt] = __builtin_amdgcn_mfma_f32_16x16x32_f16(pa[0][1], v1, oacc[0][dt], 0, 0, 0);
      oacc[1][dt] = __builtin_amdgcn_mfma_f32_16x16x32_f16(pa[1][0], v0, oacc[1][dt], 0, 0, 0);
      oacc[1][dt] = __builtin_amdgcn_mfma_f32_16x16x32_f16(pa[1][1], v1, oacc[1][dt], 0, 0, 0);
    }
    __builtin_amdgcn_s_setprio(0);

    asm volatile("s_waitcnt vmcnt(0)" ::: "memory");
    __syncthreads();
  }

  // ---- epilogue: one deferred row-sum reduce, normalize, write fp16 ----
  half_t* Ob = O + ((size_t)(b * NL) + qrow0) * (NH * NHD) + (size_t)h * NHD;
#pragma unroll
  for (int rt = 0; rt < 2; ++rt)
#pragma unroll
    for (int i = 0; i < 4; ++i) {
      float l = lsum[rt][i];
#pragma unroll
      for (int off = 1; off < 16; off <<= 1)
        l += __shfl_xor(l, off);
      const float inv = 1.0f / l;
      const int rl = rt * 16 + quad * 4 + i;
#pragma unroll
      for (int dt = 0; dt < 8; ++dt)
        Ob[(size_t)rl * (NH * NHD) + dt * 16 + r16] =
            (half_t)(oacc[rt][dt][i] * inv);
    }
}

// ---------------------------------------------------------------------------
extern "C" void kernel_launch(void* const* d_in, const int* in_sizes, int n_in,
                              void* d_out, int out_size, void* d_ws, size_t ws_size,
                              hipStream_t stream) {
  const float* x  = (const float*)d_in[0];
  const float* Wq = (const float*)d_in[1];
  const float* bq = (const float*)d_in[2];
  const float* Wk = (const float*)d_in[3];
  const float* bk = (const float*)d_in[4];
  const float* Wv = (const float*)d_in[5];
  const float* bv = (const float*)d_in[6];
  const float* Wo = (const float*)d_in[7];
  float* out = (float*)d_out;

  char* ws = (char*)d_ws;
  size_t off = 0;
  auto alloc = [&](size_t bytes) {
    size_t cur = off;
    off += (bytes + 255) & ~(size_t)255;
    return cur;
  };
  const size_t M = (size_t)NB * NL;  // 4096 token rows
  // buffer plan (~186 MB):
  half_t* xb   = (half_t*)(ws + alloc(M * ND * 2));            // x fp16; reused as AttnOut
  half_t* wqkv = (half_t*)(ws + alloc((size_t)NQKV * ND * 2)); // [Wq;Wk;Wv]^T; reused for Wo^T
  half_t* rawh = (half_t*)(ws + alloc(M * NQKV * 2));          // merged QKV raw fp16
  half_t* qb   = (half_t*)(ws + alloc(M * (size_t)(NH * NHD) * 2));
  half_t* kb   = (half_t*)(ws + alloc(M * (size_t)(NKV * NHD) * 2));
  half_t* vt   = (half_t*)(ws + alloc(M * (size_t)(NKV * NHD) * 2));
  float2* tab  = (float2*)(ws + alloc((size_t)NL * 64 * 8));   // RoPE cos/sin

  // 1) x -> fp16 ; RoPE table
  {
    int n4 = (int)(M * ND / 4);
    convert_f32_f16_kernel<<<dim3((n4 + 255) / 256), dim3(256), 0, stream>>>(x, xb, n4);
  }
  ropetab_kernel<<<dim3(NL * 64 / 256), dim3(256), 0, stream>>>(tab);

  // 2) weight transposes into merged [6144][4096] fp16 (vectorized, block (8,32))
  wtrans_kernel<<<dim3(ND / 32, ND / 32), dim3(8, 32), 0, stream>>>(
      Wq, wqkv, ND, ND);
  wtrans_kernel<<<dim3((NKV * NHD) / 32, ND / 32), dim3(8, 32), 0, stream>>>(
      Wk, wqkv + (size_t)ND * ND, ND, NKV * NHD);
  wtrans_kernel<<<dim3((NKV * NHD) / 32, ND / 32), dim3(8, 32), 0, stream>>>(
      Wv, wqkv + (size_t)(ND + NKV * NHD) * ND, ND, NKV * NHD);

  // 3) merged QKV GEMM -> rawh fp16 (bias fused, 3-way select)
  gemm256_kernel<half_t><<<dim3(NQKV / 256, M / 256), dim3(512), 0, stream>>>(
      xb, wqkv, bq, bk, bv, rawh, (int)M, NQKV, ND);

  // 4) RoPE+pack Q,K (table-driven, 4 d/thread); transpose V (vectorized)
  ropepack_kernel<<<dim3((unsigned)(M * (NH + NKV) * 16 / 256)), dim3(256), 0, stream>>>(
      rawh, tab, qb, kb);
  vtrans16_kernel<<<dim3(NL / 32, NHD / 32, NB * NKV), dim3(8, 32), 0, stream>>>(rawh, vt);

  // 5) Wo^T into wqkv (dead after step 3; stream order guarantees safety)
  wtrans_kernel<<<dim3(ND / 32, ND / 32), dim3(8, 32), 0, stream>>>(Wo, wqkv, NH * NHD, ND);

  // 6) attention -> xb (reused as AttnOut, [B*L, H*HD] fp16)
  attn_kernel<<<dim3(NB * NH * (NL / 256)), dim3(512), 0, stream>>>(qb, kb, vt, xb);

  // 7) output projection -> d_out (fp32)
  gemm256_kernel<float><<<dim3(ND / 256, M / 256), dim3(512), 0, stream>>>(
      xb, wqkv, nullptr, nullptr, nullptr, out, (int)M, ND, ND);
}

// Round 17
// 638.435 us; speedup vs baseline: 1.4012x; 1.0003x over previous
//
#include <hip/hip_runtime.h>
#include <stdint.h>
#include <stddef.h>

// ---------------------------------------------------------------------------
// Fused GQA attention block: QKV proj + half-split RoPE + flash attention +
// output proj. fp16 MFMA (16x16x32) everywhere, fp32 accumulate/softmax.
// R17 = R16 (verified best, 638.7us) held as final: measured structural
// optimum of this decomposition.
// Schedule-space record: GEMM 2-phase/lgkm0-before-barrier (R11) is the
// measured optimum (40% MfmaUtil; 1-barrier=25%, 8-barrier=34.5%,
// reg-pipeline=29%); 2 waves/SIMD is register-capped (128 AGPR acc + 104
// VGPR). Attn 2-blocks/CU infeasible (oacc AGPR + VGPR ~164/wave); KVB=32
// -12%; KVB=128 exceeds LDS. Next-session levers: swapped-QK^T in-register
// softmax (T12); producer-consumer wave-specialized GEMM.
// ---------------------------------------------------------------------------

typedef _Float16 half_t;
typedef __attribute__((ext_vector_type(4))) _Float16 f16x4;
typedef __attribute__((ext_vector_type(8))) _Float16 f16x8;
typedef __attribute__((ext_vector_type(4))) float f32x4;

#define NB 2
#define NL 2048
#define ND 4096
#define NH 32
#define NKV 8
#define NHD 128
#define NG 4               // H / KV
#define NQKV 6144          // H*HD + 2*KV*HD
#define QK_SCALE 0.08838834764831845f   // HD^-0.5
#define RLOG2E 1.4426950408889634f
#define M0 6.0f            // fixed softmax reference (scores ~N(0,1.64^2))
#define THR 8.0f           // defer-max threshold (fallback if mx > M0+THR)

// async global->LDS, 16B per lane. LDS dest must be wave-uniform base;
// lane i lands at base + i*16 (HW-defined linear scatter).
static __device__ __forceinline__ void gll16(const void* g, void* l) {
  __builtin_amdgcn_global_load_lds(
      (__attribute__((address_space(1))) void*)(void*)(g),
      (__attribute__((address_space(3))) void*)(l),
      16, 0, 0);
}

// ---------------------------------------------------------------------------
// elementwise fp32 -> fp16 (vectorized: float4 in, 4xfp16 out)
// ---------------------------------------------------------------------------
__global__ void convert_f32_f16_kernel(const float* __restrict__ in,
                                       half_t* __restrict__ out, int n4) {
  int i = blockIdx.x * 256 + threadIdx.x;
  if (i >= n4) return;
  const float4 v = reinterpret_cast<const float4*>(in)[i];
  f16x4 o;
  o[0] = (half_t)v.x; o[1] = (half_t)v.y; o[2] = (half_t)v.z; o[3] = (half_t)v.w;
  reinterpret_cast<f16x4*>(out)[i] = o;
}

// ---------------------------------------------------------------------------
// W [K,N] fp32 row-major -> Wt [N,K] fp16 row-major. Block (8,32),
// float4 loads (16B/lane), f16x4 stores (8B/lane).
// load: tile[l=ty][c=tx*4+j] = W[k0+ty][n0+tx*4+j]
// store: Wt[n0+ty][k0+tx*4+j] = tile[tx*4+j][ty]  (transpose verified)
// Store-read bank: ((tx*4+j)*33+ty)%32 -> <=2-way (free).
// ---------------------------------------------------------------------------
__global__ void wtrans_kernel(const float* __restrict__ W,
                              half_t* __restrict__ Wt, int K, int N) {
  __shared__ float tile[32][33];
  const int n0 = blockIdx.x * 32;
  const int k0 = blockIdx.y * 32;
  const int tx = threadIdx.x, ty = threadIdx.y;   // block (8,32)
  const float4 v = *reinterpret_cast<const float4*>(
      &W[(size_t)(k0 + ty) * N + n0 + tx * 4]);
  tile[ty][tx * 4 + 0] = v.x;
  tile[ty][tx * 4 + 1] = v.y;
  tile[ty][tx * 4 + 2] = v.z;
  tile[ty][tx * 4 + 3] = v.w;
  __syncthreads();
  f16x4 o;
#pragma unroll
  for (int j = 0; j < 4; ++j)
    o[j] = (half_t)tile[tx * 4 + j][ty];
  *reinterpret_cast<f16x4*>(&Wt[(size_t)(n0 + ty) * K + k0 + tx * 4]) = o;
}

// ---------------------------------------------------------------------------
// RoPE sin/cos table: tab[l*64+d] = {cos(l*invfreq(d)), sin(l*invfreq(d))}
// ---------------------------------------------------------------------------
__global__ void ropetab_kernel(float2* __restrict__ tab) {
  const int idx = blockIdx.x * 256 + threadIdx.x;   // NL*64 entries
  const int d = idx & 63;
  const int l = idx >> 6;
  const float inv_freq = exp2f(-(float)d * 0.20762050593045935f);
  const float ang = (float)l * inv_freq;
  float sn, cs;
  __sincosf(ang, &sn, &cs);
  tab[idx] = make_float2(cs, sn);
}

// ---------------------------------------------------------------------------
// GEMM (R11, best measured): 256x256 tile, 8 waves, BK=64 as 2 K-halves,
// 2 phases/K-tile, 32 MFMA/phase, one barrier + one combined vmcnt+lgkm wait
// per phase.
// RAW: (t)k0 retired by PB(t-1)'s vmcnt(8)+barrier; (t)k1 by PA(t)'s
// vmcnt(8)+barrier. WAR: lgkm0 BEFORE each barrier pins every wave's reads;
// the slot staged in the next phase cannot race them.
// Swizzle: global chunk cg at LDS chunk cg^((row>>1)&3); reads use
// csw = (quad ^ ((r16>>1)&3)) -> measured 0 bank conflicts.
// ---------------------------------------------------------------------------
template <typename OutT>
__global__ __launch_bounds__(512, 2) void gemm256_kernel(
    const half_t* __restrict__ A, const half_t* __restrict__ Bt,
    const float* __restrict__ B0, const float* __restrict__ B1,
    const float* __restrict__ B2, OutT* __restrict__ C,
    int M, int N, int K) {
  __shared__ __align__(16) half_t As[2][2][256 * 32];   // [buf][kh] 16KB each
  __shared__ __align__(16) half_t Bs[2][2][256 * 32];

  const int tid = threadIdx.x;
  const int wave = tid >> 6, lane = tid & 63;
  const int r16 = lane & 15, quad = lane >> 4;
  const int wm = wave >> 2, wn = wave & 3;   // 2M x 4N wave grid

  // T1: XCD-chunked swizzle of linear block id (nwg % 8 == 0 for our grids)
  const int nbx = N >> 8;
  const int lid = (int)(blockIdx.y * gridDim.x + blockIdx.x);
  const int nwg = (int)(gridDim.x * gridDim.y);
  const int cpx = nwg >> 3;
  const int swz = (lid & 7) * cpx + (lid >> 3);
  const int brow = (swz / nbx) * 256;
  const int bcol = (swz % nbx) * 256;

  const int NT = K >> 6;   // K/64 tiles

  auto stA = [&](int t, int kh) {
    const int buf = t & 1;
    const int k0 = (t << 6) + (kh << 5);
#pragma unroll
    for (int j = 0; j < 2; ++j) {
      const int s = j * 512 + wave * 64 + lane;
      const int row = s >> 2;
      const int cg = (s & 3) ^ ((row >> 1) & 3);
      gll16(A + (size_t)(brow + row) * K + k0 + cg * 8,
            &As[buf][kh][(j * 512 + wave * 64) * 8]);
    }
  };
  auto stB = [&](int t, int kh) {
    const int buf = t & 1;
    const int k0 = (t << 6) + (kh << 5);
#pragma unroll
    for (int j = 0; j < 2; ++j) {
      const int s = j * 512 + wave * 64 + lane;
      const int row = s >> 2;
      const int cg = (s & 3) ^ ((row >> 1) & 3);
      gll16(Bt + (size_t)(bcol + row) * K + k0 + cg * 8,
            &Bs[buf][kh][(j * 512 + wave * 64) * 8]);
    }
  };

  f32x4 acc[8][4] = {};
  const int csw = (quad ^ ((r16 >> 1) & 3)) << 3;   // swizzled chunk (halfs)

  stA(0, 0); stB(0, 0); stA(0, 1); stB(0, 1); stA(1, 0); stB(1, 0);
  asm volatile("s_waitcnt vmcnt(8)" ::: "memory");
  __builtin_amdgcn_s_barrier();

  for (int t = 0; t < NT; ++t) {
    const int buf = t & 1;
    const half_t* Ak0 = &As[buf][0][0];
    const half_t* Ak1 = &As[buf][1][0];
    const half_t* Bk0 = &Bs[buf][0][0];
    const half_t* Bk1 = &Bs[buf][1][0];
    f16x8 af[4], bf[4], ah[4];

    // ============ PA: kc0, 32 MFMA ============
#pragma unroll
    for (int mi = 0; mi < 4; ++mi)
      af[mi] = *reinterpret_cast<const f16x8*>(
          &Ak0[(wm * 128 + mi * 16 + r16) * 32 + csw]);
#pragma unroll
    for (int ni = 0; ni < 4; ++ni)
      bf[ni] = *reinterpret_cast<const f16x8*>(
          &Bk0[(wn * 64 + ni * 16 + r16) * 32 + csw]);
#pragma unroll
    for (int mi = 0; mi < 4; ++mi)
      ah[mi] = *reinterpret_cast<const f16x8*>(
          &Ak0[(wm * 128 + 64 + mi * 16 + r16) * 32 + csw]);
    if (t + 1 < NT) {
      stA(t + 1, 1); stB(t + 1, 1);
      asm volatile("s_waitcnt vmcnt(8) lgkmcnt(0)" ::: "memory");
    } else {
      asm volatile("s_waitcnt vmcnt(4) lgkmcnt(0)" ::: "memory");
    }
    __builtin_amdgcn_sched_barrier(0);
    __builtin_amdgcn_s_barrier();
    __builtin_amdgcn_sched_barrier(0);
    __builtin_amdgcn_s_setprio(1);
#pragma unroll
    for (int mi = 0; mi < 4; ++mi)
#pragma unroll
      for (int ni = 0; ni < 4; ++ni)
        acc[mi][ni] = __builtin_amdgcn_mfma_f32_16x16x32_f16(
            af[mi], bf[ni], acc[mi][ni], 0, 0, 0);
#pragma unroll
    for (int mi = 0; mi < 4; ++mi)
#pragma unroll
      for (int ni = 0; ni < 4; ++ni)
        acc[mi + 4][ni] = __builtin_amdgcn_mfma_f32_16x16x32_f16(
            ah[mi], bf[ni], acc[mi + 4][ni], 0, 0, 0);
    __builtin_amdgcn_s_setprio(0);

    // ============ PB: kc1, 32 MFMA ============
#pragma unroll
    for (int mi = 0; mi < 4; ++mi)
      af[mi] = *reinterpret_cast<const f16x8*>(
          &Ak1[(wm * 128 + mi * 16 + r16) * 32 + csw]);
#pragma unroll
    for (int ni = 0; ni < 4; ++ni)
      bf[ni] = *reinterpret_cast<const f16x8*>(
          &Bk1[(wn * 64 + ni * 16 + r16) * 32 + csw]);
#pragma unroll
    for (int mi = 0; mi < 4; ++mi)
      ah[mi] = *reinterpret_cast<const f16x8*>(
          &Ak1[(wm * 128 + 64 + mi * 16 + r16) * 32 + csw]);
    if (t + 2 < NT) {
      stA(t + 2, 0); stB(t + 2, 0);
      asm volatile("s_waitcnt vmcnt(8) lgkmcnt(0)" ::: "memory");
    } else if (t + 1 < NT) {
      asm volatile("s_waitcnt vmcnt(8) lgkmcnt(0)" ::: "memory");
    } else {
      asm volatile("s_waitcnt vmcnt(0) lgkmcnt(0)" ::: "memory");
    }
    __builtin_amdgcn_sched_barrier(0);
    __builtin_amdgcn_s_barrier();
    __builtin_amdgcn_sched_barrier(0);
    __builtin_amdgcn_s_setprio(1);
#pragma unroll
    for (int mi = 0; mi < 4; ++mi)
#pragma unroll
      for (int ni = 0; ni < 4; ++ni)
        acc[mi][ni] = __builtin_amdgcn_mfma_f32_16x16x32_f16(
            af[mi], bf[ni], acc[mi][ni], 0, 0, 0);
#pragma unroll
    for (int mi = 0; mi < 4; ++mi)
#pragma unroll
      for (int ni = 0; ni < 4; ++ni)
        acc[mi + 4][ni] = __builtin_amdgcn_mfma_f32_16x16x32_f16(
            ah[mi], bf[ni], acc[mi + 4][ni], 0, 0, 0);
    __builtin_amdgcn_s_setprio(0);
  }

  // epilogue: D row = (lane>>4)*4 + reg, col = lane&15 (verified C/D layout)
#pragma unroll
  for (int ni = 0; ni < 4; ++ni) {
    const int col = bcol + wn * 64 + ni * 16 + r16;
    float bv = 0.0f;
    if (B0) bv = (col < ND) ? B0[col]
                            : (col < ND + NKV * NHD ? B1[col - ND]
                                                    : B2[col - ND - NKV * NHD]);
#pragma unroll
    for (int mi = 0; mi < 8; ++mi) {
      const int row0 = brow + wm * 128 + mi * 16 + quad * 4;
#pragma unroll
      for (int i = 0; i < 4; ++i)
        C[(size_t)(row0 + i) * N + col] = (OutT)(acc[mi][ni][i] + bv);
    }
  }
}

// ---------------------------------------------------------------------------
// RoPE (half-split, table-driven) + reshape for Q and K from merged raw fp16.
// 4 d-values per thread — 8B vector loads/stores (G13), 4x fewer threads.
// hp<32: Q head hp (QK_SCALE folded); else K head hp-32.
// ---------------------------------------------------------------------------
__global__ void ropepack_kernel(const half_t* __restrict__ rawh,
                                const float2* __restrict__ tab,
                                half_t* __restrict__ qb,
                                half_t* __restrict__ kb) {
  const size_t idx = (size_t)blockIdx.x * 256 + threadIdx.x;
  const int d0 = (int)(idx & 15) * 4;          // d0, d0+1, d0+2, d0+3
  size_t t = idx >> 4;
  const int hp = (int)(t % (NH + NKV)); t /= (NH + NKV);
  const int l = (int)(t % NL);
  const int b = (int)(t / NL);
  const bool isQ = hp < NH;
  const int col0 = isQ ? hp * NHD : ND + (hp - NH) * NHD;
  const half_t* src = rawh + ((size_t)b * NL + l) * NQKV + col0;
  const f16x4 x1v = *reinterpret_cast<const f16x4*>(&src[d0]);
  const f16x4 x2v = *reinterpret_cast<const f16x4*>(&src[d0 + 64]);
  const float scale = isQ ? QK_SCALE : 1.0f;
  half_t* dst = isQ ? qb + ((size_t)(b * NH + hp) * NL + l) * NHD
                    : kb + ((size_t)(b * NKV + (hp - NH)) * NL + l) * NHD;
  f16x4 o1, o2;
#pragma unroll
  for (int j = 0; j < 4; ++j) {
    const float2 cssn = tab[(size_t)l * 64 + d0 + j];
    const float x1 = (float)x1v[j];
    const float x2 = (float)x2v[j];
    o1[j] = (half_t)((x1 * cssn.x - x2 * cssn.y) * scale);
    o2[j] = (half_t)((x2 * cssn.x + x1 * cssn.y) * scale);
  }
  *reinterpret_cast<f16x4*>(&dst[d0])      = o1;
  *reinterpret_cast<f16x4*>(&dst[d0 + 64]) = o2;
}

// ---------------------------------------------------------------------------
// V: merged raw fp16 cols [5120,6144) -> Vt [B, KV, HD, L] fp16.
// Block (8,32), f16x4 loads/stores (8B/lane). [34]-pad -> conflict-free.
// ---------------------------------------------------------------------------
__global__ void vtrans16_kernel(const half_t* __restrict__ rawh,
                                half_t* __restrict__ Vt) {
  __shared__ half_t tile[32][34];
  const int bkv = blockIdx.z;
  const int l0 = blockIdx.x * 32;
  const int d0 = blockIdx.y * 32;
  const int b = bkv / NKV, kvh = bkv % NKV;
  const int tx = threadIdx.x, ty = threadIdx.y;   // block (8,32)
  const f16x4 v = *reinterpret_cast<const f16x4*>(
      &rawh[(size_t)(b * NL + l0 + ty) * NQKV
            + ND + NKV * NHD + kvh * NHD + d0 + tx * 4]);
#pragma unroll
  for (int j = 0; j < 4; ++j) tile[ty][tx * 4 + j] = v[j];
  __syncthreads();
  half_t* dst = Vt + (size_t)bkv * NHD * NL;
  f16x4 o;
#pragma unroll
  for (int j = 0; j < 4; ++j) o[j] = tile[tx * 4 + j][ty];
  *reinterpret_cast<f16x4*>(&dst[(size_t)(d0 + ty) * NL + l0 + tx * 4]) = o;
}

// ---------------------------------------------------------------------------
// Flash attention (non-causal, GQA). 8 waves x 32 Q-rows = 256 rows/block.
// R11 version (best measured): KVB=64, K/V double-buffered in LDS (80KB),
// XOR chunk-swizzled, fixed-ref M0 softmax with per-lane deferred row-sum +
// rare wave-uniform fallback rescale, T5 setprio on MFMA clusters.
// ---------------------------------------------------------------------------
#define KVB 64

__global__ __launch_bounds__(512, 2) void attn_kernel(
    const half_t* __restrict__ Q,   // [B,H,L,HD] scaled
    const half_t* __restrict__ Kh,  // [B,KV,L,HD]
    const half_t* __restrict__ Vt,  // [B,KV,HD,L]
    half_t* __restrict__ O) {
  __shared__ half_t Ks[2][KVB * NHD];   // 2 x 16KB
  __shared__ half_t Vs[2][NHD * KVB];   // 2 x 16KB
  __shared__ half_t Ps[8][16 * 64];     // 16KB, per-wave P tile

  const int tid = threadIdx.x;
  const int wave = tid >> 6, lane = tid & 63;
  const int r16 = lane & 15, quad = lane >> 4;
  const int r7 = r16 & 7;

  // XCD-chunked swizzle: 64 consecutive work-items per XCD (512 = 8*64)
  const int bid = (int)blockIdx.x;
  const int swz = (bid & 7) * 64 + (bid >> 3);
  const int nqt = NL / 256;                    // 8
  const int bh = swz / nqt, qt = swz % nqt;
  const int b = bh / NH, h = bh % NH;
  const int kvh = h / NG;

  const int qrow0 = qt * 256 + wave * 32;
  const half_t* Qb = Q  + ((size_t)(b * NH + h) * NL + qrow0) * NHD;
  const half_t* Kb = Kh + ((size_t)(b * NKV + kvh) * NL) * NHD;
  const half_t* Vb = Vt + ((size_t)(b * NKV + kvh) * NHD) * NL;
  half_t* Pw = &Ps[wave][0];

  // ---- stage(buf, n0): K tile 1024 slots, V tile 1024 slots (16B each) ----
  auto stage = [&](int buf, int n0) {
#pragma unroll
    for (int j = 0; j < 2; ++j) {
      const int slot = j * 512 + wave * 64 + lane;
      {
        const int row = slot >> 4;                    // key row 0..63
        const int c = (slot & 15) ^ (row & 7);        // global chunk
        gll16(Kb + (size_t)(n0 + row) * NHD + c * 8,
              &Ks[buf][(j * 512 + wave * 64) * 8]);
      }
      {
        const int row = slot >> 3;                    // d row 0..127
        const int c = (slot & 7) ^ (row & 7);
        gll16(Vb + (size_t)row * NL + n0 + c * 8,
              &Vs[buf][(j * 512 + wave * 64) * 8]);
      }
    }
  };

  stage(0, 0);

  // Q fragments: 2 row-tiles x 4 k-chunks
  f16x8 qf[2][4];
#pragma unroll
  for (int rt = 0; rt < 2; ++rt)
#pragma unroll
    for (int c = 0; c < 4; ++c)
      qf[rt][c] = *reinterpret_cast<const f16x8*>(
          &Qb[(size_t)(rt * 16 + r16) * NHD + c * 32 + quad * 8]);

  f32x4 oacc[2][8];
  float m_run[2][4], lsum[2][4];
#pragma unroll
  for (int rt = 0; rt < 2; ++rt) {
#pragma unroll
    for (int i = 0; i < 4; ++i) { m_run[rt][i] = M0; lsum[rt][i] = 0.0f; }
#pragma unroll
    for (int dt = 0; dt < 8; ++dt) oacc[rt][dt] = (f32x4){0.f, 0.f, 0.f, 0.f};
  }

  // P read swizzle (row = r16): mask = (r16&7) ^ ((r16>>3)*5)
  const int swzread = r7 ^ ((r16 >> 3) * 5);

  asm volatile("s_waitcnt vmcnt(0)" ::: "memory");
  __syncthreads();

  int cur = 0;
  for (int t = 0; t < NL / KVB; ++t, cur ^= 1) {
    if (t + 1 < NL / KVB) stage(cur ^ 1, (t + 1) * KVB);

    const half_t* Kc = &Ks[cur][0];
    const half_t* Vc = &Vs[cur][0];

    // ---- S = Q K^T (swizzled K reads) ----
    f32x4 s[2][4] = {};
    __builtin_amdgcn_s_setprio(1);
#pragma unroll
    for (int c = 0; c < 4; ++c) {
      const int ch = ((c * 4 + quad) ^ r7) * 8;
#pragma unroll
      for (int nt = 0; nt < 4; ++nt) {
        f16x8 kf = *reinterpret_cast<const f16x8*>(&Kc[(nt * 16 + r16) * NHD + ch]);
        s[0][nt] = __builtin_amdgcn_mfma_f32_16x16x32_f16(qf[0][c], kf, s[0][nt], 0, 0, 0);
        s[1][nt] = __builtin_amdgcn_mfma_f32_16x16x32_f16(qf[1][c], kf, s[1][nt], 0, 0, 0);
      }
    }
    __builtin_amdgcn_s_setprio(0);

    // ---- fallback check: any lane-local score above running ref? ----
    float mx[2][4];
    bool need = false;
#pragma unroll
    for (int rt = 0; rt < 2; ++rt)
#pragma unroll
      for (int i = 0; i < 4; ++i) {
        mx[rt][i] = fmaxf(fmaxf(s[rt][0][i], s[rt][1][i]),
                          fmaxf(s[rt][2][i], s[rt][3][i]));
        need = need || (mx[rt][i] > m_run[rt][i] + THR);
      }
    if (__any(need ? 1 : 0)) {   // rare: full reduce + rescale (correctness)
#pragma unroll
      for (int rt = 0; rt < 2; ++rt)
#pragma unroll
        for (int i = 0; i < 4; ++i) {
          float m = mx[rt][i];
#pragma unroll
          for (int off = 1; off < 16; off <<= 1)
            m = fmaxf(m, __shfl_xor(m, off));
          const float mn = fmaxf(m_run[rt][i], m);
          const float corr = exp2f((m_run[rt][i] - mn) * RLOG2E);
          m_run[rt][i] = mn;
          lsum[rt][i] *= corr;
#pragma unroll
          for (int dt = 0; dt < 8; ++dt) oacc[rt][dt][i] *= corr;
        }
    }

    // ---- P = exp(S - m), per-lane partial sums, swizzled LDS writes ----
    f16x8 pa[2][2];
#pragma unroll
    for (int rt = 0; rt < 2; ++rt) {
#pragma unroll
      for (int i = 0; i < 4; ++i) {
        const float mrl = m_run[rt][i] * RLOG2E;
        float p[4];
#pragma unroll
        for (int nt = 0; nt < 4; ++nt)
          p[nt] = exp2f(s[rt][nt][i] * RLOG2E - mrl);
        lsum[rt][i] += (p[0] + p[1]) + (p[2] + p[3]);
        const int row = quad * 4 + i;
        const int swzr = (row & 7) ^ ((row >> 3) * 5);
#pragma unroll
        for (int nt = 0; nt < 4; ++nt)
          Pw[row * 64 + (((nt * 2 + (r16 >> 3)) ^ swzr) * 8) + r7] = (half_t)p[nt];
      }
      // A-fragments (wave-private LDS; in-order DS pipe, no barrier)
      pa[rt][0] = *reinterpret_cast<const f16x8*>(&Pw[r16 * 64 + ((quad ^ swzread) * 8)]);
      pa[rt][1] = *reinterpret_cast<const f16x8*>(&Pw[r16 * 64 + (((4 + quad) ^ swzread) * 8)]);
    }

    // ---- O += P V (swizzled V reads, shared across both row-tiles) ----
    const int ch0 = (quad ^ r7) * 8;
    const int ch1 = ((4 + quad) ^ r7) * 8;
    __builtin_amdgcn_s_setprio(1);
#pragma unroll
    for (int dt = 0; dt < 8; ++dt) {
      const int row = dt * 16 + r16;
      f16x8 v0 = *reinterpret_cast<const f16x8*>(&Vc[row * 64 + ch0]);
      f16x8 v1 = *reinterpret_cast<const f16x8*>(&Vc[row * 64 + ch1]);
      oacc[0][dt] = __builtin_amdgcn_mfma_f32_16x16x32_f16(pa[0][0], v0, oacc[0][dt], 0, 0, 0);
      oacc[0][dt] = __builtin_amdgcn_mfma_f32_16x16x32_f16(pa[0][1], v1, oacc[0][dt], 0, 0, 0);
      oacc[1][dt] = __builtin_amdgcn_mfma_f32_16x16x32_f16(pa[1][0], v0, oacc[1][dt], 0, 0, 0);
      oacc[1][dt] = __builtin_amdgcn_mfma_f32_16x16x32_f16(pa[1][1], v1, oacc[1][dt], 0, 0, 0);
    }
    __builtin_amdgcn_s_setprio(0);

    asm volatile("s_waitcnt vmcnt(0)" ::: "memory");
    __syncthreads();
  }

  // ---- epilogue: one deferred row-sum reduce, normalize, write fp16 ----
  half_t* Ob = O + ((size_t)(b * NL) + qrow0) * (NH * NHD) + (size_t)h * NHD;
#pragma unroll
  for (int rt = 0; rt < 2; ++rt)
#pragma unroll
    for (int i = 0; i < 4; ++i) {
      float l = lsum[rt][i];
#pragma unroll
      for (int off = 1; off < 16; off <<= 1)
        l += __shfl_xor(l, off);
      const float inv = 1.0f / l;
      const int rl = rt * 16 + quad * 4 + i;
#pragma unroll
      for (int dt = 0; dt < 8; ++dt)
        Ob[(size_t)rl * (NH * NHD) + dt * 16 + r16] =
            (half_t)(oacc[rt][dt][i] * inv);
    }
}

// ---------------------------------------------------------------------------
extern "C" void kernel_launch(void* const* d_in, const int* in_sizes, int n_in,
                              void* d_out, int out_size, void* d_ws, size_t ws_size,
                              hipStream_t stream) {
  const float* x  = (const float*)d_in[0];
  const float* Wq = (const float*)d_in[1];
  const float* bq = (const float*)d_in[2];
  const float* Wk = (const float*)d_in[3];
  const float* bk = (const float*)d_in[4];
  const float* Wv = (const float*)d_in[5];
  const float* bv = (const float*)d_in[6];
  const float* Wo = (const float*)d_in[7];
  float* out = (float*)d_out;

  char* ws = (char*)d_ws;
  size_t off = 0;
  auto alloc = [&](size_t bytes) {
    size_t cur = off;
    off += (bytes + 255) & ~(size_t)255;
    return cur;
  };
  const size_t M = (size_t)NB * NL;  // 4096 token rows
  // buffer plan (~186 MB):
  half_t* xb   = (half_t*)(ws + alloc(M * ND * 2));            // x fp16; reused as AttnOut
  half_t* wqkv = (half_t*)(ws + alloc((size_t)NQKV * ND * 2)); // [Wq;Wk;Wv]^T; reused for Wo^T
  half_t* rawh = (half_t*)(ws + alloc(M * NQKV * 2));          // merged QKV raw fp16
  half_t* qb   = (half_t*)(ws + alloc(M * (size_t)(NH * NHD) * 2));
  half_t* kb   = (half_t*)(ws + alloc(M * (size_t)(NKV * NHD) * 2));
  half_t* vt   = (half_t*)(ws + alloc(M * (size_t)(NKV * NHD) * 2));
  float2* tab  = (float2*)(ws + alloc((size_t)NL * 64 * 8));   // RoPE cos/sin

  // 1) x -> fp16 ; RoPE table
  {
    int n4 = (int)(M * ND / 4);
    convert_f32_f16_kernel<<<dim3((n4 + 255) / 256), dim3(256), 0, stream>>>(x, xb, n4);
  }
  ropetab_kernel<<<dim3(NL * 64 / 256), dim3(256), 0, stream>>>(tab);

  // 2) weight transposes into merged [6144][4096] fp16 (vectorized, block (8,32))
  wtrans_kernel<<<dim3(ND / 32, ND / 32), dim3(8, 32), 0, stream>>>(
      Wq, wqkv, ND, ND);
  wtrans_kernel<<<dim3((NKV * NHD) / 32, ND / 32), dim3(8, 32), 0, stream>>>(
      Wk, wqkv + (size_t)ND * ND, ND, NKV * NHD);
  wtrans_kernel<<<dim3((NKV * NHD) / 32, ND / 32), dim3(8, 32), 0, stream>>>(
      Wv, wqkv + (size_t)(ND + NKV * NHD) * ND, ND, NKV * NHD);

  // 3) merged QKV GEMM -> rawh fp16 (bias fused, 3-way select)
  gemm256_kernel<half_t><<<dim3(NQKV / 256, M / 256), dim3(512), 0, stream>>>(
      xb, wqkv, bq, bk, bv, rawh, (int)M, NQKV, ND);

  // 4) RoPE+pack Q,K (table-driven, 4 d/thread); transpose V (vectorized)
  ropepack_kernel<<<dim3((unsigned)(M * (NH + NKV) * 16 / 256)), dim3(256), 0, stream>>>(
      rawh, tab, qb, kb);
  vtrans16_kernel<<<dim3(NL / 32, NHD / 32, NB * NKV), dim3(8, 32), 0, stream>>>(rawh, vt);

  // 5) Wo^T into wqkv (dead after step 3; stream order guarantees safety)
  wtrans_kernel<<<dim3(ND / 32, ND / 32), dim3(8, 32), 0, stream>>>(Wo, wqkv, NH * NHD, ND);

  // 6) attention -> xb (reused as AttnOut, [B*L, H*HD] fp16)
  attn_kernel<<<dim3(NB * NH * (NL / 256)), dim3(512), 0, stream>>>(qb, kb, vt, xb);

  // 7) output projection -> d_out (fp32)
  gemm256_kernel<float><<<dim3(ND / 256, M / 256), dim3(512), 0, stream>>>(
      xb, wqkv, nullptr, nullptr, nullptr, out, (int)M, ND, ND);
}